// Round 1
// baseline (1072.063 us; speedup 1.0000x reference)
//
#include <hip/hip_runtime.h>
#include <cstdint>

#define B_   8
#define C_   256
#define NQ_  1024
#define NK_  4096
#define S_   16
#define H_   8
#define FF_  2048
#define DH_  32
#define BQ_  (B_*NQ_)
#define EPS_ 1e-5f

// ---------------- generic tiled transpose of last two dims ----------------
// in: (Z, RI, CJ) -> out: (Z, CJ, RI).  grid: (CJ/32, RI/32, Z), block (32,8)
__global__ __launch_bounds__(256) void k_transpose(const float* __restrict__ in,
                                                   float* __restrict__ out,
                                                   int RI, int CJ) {
  __shared__ float t[32][33];
  int z = blockIdx.z;
  int j0 = blockIdx.x * 32, i0 = blockIdx.y * 32;
  const float* inz = in + (size_t)z * RI * CJ;
  float* outz = out + (size_t)z * RI * CJ;
  int tx = threadIdx.x, ty = threadIdx.y;
#pragma unroll
  for (int r = 0; r < 32; r += 8)
    t[ty + r][tx] = inz[(size_t)(i0 + ty + r) * CJ + (j0 + tx)];
  __syncthreads();
#pragma unroll
  for (int r = 0; r < 32; r += 8)
    outz[(size_t)(j0 + ty + r) * RI + (i0 + tx)] = t[tx][ty + r];
}

// ---------------- qin = qtok + query_pos @ qpe_w.T + qpe_b ----------------
__global__ __launch_bounds__(256) void k_qin(const float* __restrict__ qtok,
                                             const float* __restrict__ query_pos,
                                             const float* __restrict__ qpe_w,
                                             const float* __restrict__ qpe_b,
                                             float* __restrict__ qin) {
  int i = blockIdx.x * 256 + threadIdx.x;
  int bq = i >> 8, c = i & 255;
  const float* qp = query_pos + (size_t)bq * 6;
  const float* w  = qpe_w + (size_t)c * 6;
  float acc = qpe_b[c];
#pragma unroll
  for (int j = 0; j < 6; ++j) acc += qp[j] * w[j];
  qin[i] = qtok[i] + acc;
}

// ---------------- box query: one wave per query token ----------------
__global__ __launch_bounds__(256) void k_boxq(const float* __restrict__ key_pos,
                                              const float* __restrict__ query_pos,
                                              int* __restrict__ idxo,
                                              int* __restrict__ masko) {
  __shared__ float kp[NK_ * 3];  // 48 KB
  int b = (blockIdx.x * 4) >> 10;  // / NQ_
  const float* kpg = key_pos + (size_t)b * NK_ * 3;
  for (int t = threadIdx.x; t < NK_ * 3; t += 256) kp[t] = kpg[t];
  __syncthreads();
  int lane = threadIdx.x & 63;
  int q = blockIdx.x * 4 + (threadIdx.x >> 6);  // global (b*NQ+nq)
  const float* qp = query_pos + (size_t)q * 6;
  float cx = qp[0], cy = qp[1], cz = qp[2];
  float hx = 0.5f * qp[3], hy = 0.5f * qp[4], hz = 0.5f * qp[5];
  int* iq = idxo + (size_t)q * S_;
  int found = 0;
  for (int ch = 0; ch < NK_ / 64; ++ch) {
    int k = ch * 64 + lane;
    float dx = fabsf(kp[k * 3 + 0] - cx);
    float dy = fabsf(kp[k * 3 + 1] - cy);
    float dz = fabsf(kp[k * 3 + 2] - cz);
    bool inside = (dx <= hx) && (dy <= hy) && (dz <= hz);
    unsigned long long bal = __ballot(inside);
    if (inside) {
      int slot = found + __popcll(bal & ((1ull << lane) - 1ull));
      if (slot < S_) iq[slot] = k;
    }
    found += __popcll(bal);
    if (found >= S_) break;
  }
  if (found > S_) found = S_;
  if (lane < S_) {
    int m = (lane < found) ? 0 : 1;
    if (lane >= found) iq[lane] = 0;
    if (lane == 0) m = 0;
    masko[(size_t)q * S_ + lane] = m;
  }
}

// ---------------- fused gather + kpe + kh/vh GEMM + attention ----------------
// one block (256 threads) per query token bq
__global__ __launch_bounds__(256) void k_attn(
    const float* __restrict__ keyT,       // (B, NK, C)
    const float* __restrict__ key_pos,    // (B, NK, 3)
    const float* __restrict__ query_pos,  // (BQ, 6)
    const int* __restrict__ idx,          // (BQ, S)
    const int* __restrict__ maskb,        // (BQ, S)
    const float* __restrict__ qh,         // (BQ, C)
    const float* __restrict__ kwT, const float* __restrict__ kb,
    const float* __restrict__ vwT, const float* __restrict__ vb,
    const float* __restrict__ kpe_w, const float* __restrict__ kpe_b,
    float* __restrict__ ao) {             // (BQ, C)
  __shared__ float kv[S_][C_];
  __shared__ float khs[S_][C_];
  __shared__ float vhs[S_][C_];
  __shared__ float qrow[C_];
  __shared__ float attn_s[H_][S_];
  __shared__ float gx[S_][3];
  __shared__ int   sidx[S_];
  __shared__ int   smask[S_];

  int bq = blockIdx.x;
  int b = bq >> 10;  // NQ_=1024
  int t = threadIdx.x;

  if (t < S_) {
    int k = idx[(size_t)bq * S_ + t];
    sidx[t] = k;
    smask[t] = maskb[(size_t)bq * S_ + t];
    const float* kpp = key_pos + ((size_t)b * NK_ + k) * 3;
    const float* qp  = query_pos + (size_t)bq * 6;
    gx[t][0] = kpp[0] - qp[0];
    gx[t][1] = kpp[1] - qp[1];
    gx[t][2] = kpp[2] - qp[2];
  }
  qrow[t] = qh[(size_t)bq * C_ + t];
  __syncthreads();

  // kv[s][c] = keyT[b, idx_s, c] + gxyz_s . kpe_w[c] + kpe_b[c]
  float w0 = kpe_w[t * 3 + 0], w1 = kpe_w[t * 3 + 1], w2 = kpe_w[t * 3 + 2];
  float wbias = kpe_b[t];
#pragma unroll
  for (int s = 0; s < S_; ++s) {
    float f = keyT[((size_t)b * NK_ + sidx[s]) * C_ + t];
    kv[s][t] = f + w0 * gx[s][0] + w1 * gx[s][1] + w2 * gx[s][2] + wbias;
  }
  __syncthreads();

  // kh[s][n] = sum_k kv[s][k]*kwT[k][n] + kb[n]; vh same.  n = t.
  float acck[S_], accv[S_];
#pragma unroll
  for (int s = 0; s < S_; ++s) { acck[s] = 0.f; accv[s] = 0.f; }
  for (int k = 0; k < C_; k += 4) {
    float wk0 = kwT[(size_t)(k + 0) * C_ + t];
    float wk1 = kwT[(size_t)(k + 1) * C_ + t];
    float wk2 = kwT[(size_t)(k + 2) * C_ + t];
    float wk3 = kwT[(size_t)(k + 3) * C_ + t];
    float wv0 = vwT[(size_t)(k + 0) * C_ + t];
    float wv1 = vwT[(size_t)(k + 1) * C_ + t];
    float wv2 = vwT[(size_t)(k + 2) * C_ + t];
    float wv3 = vwT[(size_t)(k + 3) * C_ + t];
#pragma unroll
    for (int s = 0; s < S_; ++s) {
      float4 x4 = *(const float4*)&kv[s][k];
      acck[s] += x4.x * wk0 + x4.y * wk1 + x4.z * wk2 + x4.w * wk3;
      accv[s] += x4.x * wv0 + x4.y * wv1 + x4.z * wv2 + x4.w * wv3;
    }
  }
  float kbv = kb[t], vbv = vb[t];
#pragma unroll
  for (int s = 0; s < S_; ++s) {
    khs[s][t] = acck[s] + kbv;
    vhs[s][t] = accv[s] + vbv;
  }
  __syncthreads();

  // scores
  if (t < H_ * S_) {
    int h = t >> 4, s = t & (S_ - 1);
    float sc = 0.f;
#pragma unroll
    for (int d = 0; d < DH_; ++d) sc += qrow[h * DH_ + d] * khs[s][h * DH_ + d];
    sc *= 0.17677669529663687f;  // 1/sqrt(32)
    if (smask[s]) sc = -1e30f;
    attn_s[h][s] = sc;
  }
  __syncthreads();
  if (t < H_) {
    float mx = -3.4e38f;
#pragma unroll
    for (int s = 0; s < S_; ++s) mx = fmaxf(mx, attn_s[t][s]);
    float e[S_];
    float sum = 0.f;
#pragma unroll
    for (int s = 0; s < S_; ++s) { e[s] = expf(attn_s[t][s] - mx); sum += e[s]; }
    float inv = 1.f / sum;
#pragma unroll
    for (int s = 0; s < S_; ++s) attn_s[t][s] = e[s] * inv;
  }
  __syncthreads();

  int h = t >> 5;  // DH_=32
  float a = 0.f;
#pragma unroll
  for (int s = 0; s < S_; ++s) a += attn_s[h][s] * vhs[s][t];
  ao[(size_t)bq * C_ + t] = a;
}

// ---------------- generic fp32 GEMM: out = A(MxK) @ WT(KxN) + bias, opt relu --
// 64x64 tile, 256 threads, 4x4 per thread, K-tile 16
template <int RELU>
__global__ __launch_bounds__(256) void k_gemm(const float* __restrict__ A,
                                              const float* __restrict__ WT,
                                              const float* __restrict__ bias,
                                              float* __restrict__ out,
                                              int M, int N, int K) {
  __shared__ float a_lds[16][68];  // [k][m]
  __shared__ float b_lds[16][68];  // [k][n]
  int n0 = blockIdx.x * 64, m0 = blockIdx.y * 64;
  int t = threadIdx.x;
  int tx = t & 15, ty = t >> 4;
  float acc[4][4];
#pragma unroll
  for (int i = 0; i < 4; ++i)
#pragma unroll
    for (int j = 0; j < 4; ++j) acc[i][j] = 0.f;

  int ar = t >> 2, akq = (t & 3) * 4;
  int bk = t >> 4, bn = (t & 15) * 4;

  for (int k0 = 0; k0 < K; k0 += 16) {
    float4 av = *(const float4*)&A[(size_t)(m0 + ar) * K + k0 + akq];
    float4 bv = *(const float4*)&WT[(size_t)(k0 + bk) * N + n0 + bn];
    a_lds[akq + 0][ar] = av.x;
    a_lds[akq + 1][ar] = av.y;
    a_lds[akq + 2][ar] = av.z;
    a_lds[akq + 3][ar] = av.w;
    *(float4*)&b_lds[bk][bn] = bv;
    __syncthreads();
#pragma unroll
    for (int kk = 0; kk < 16; ++kk) {
      float4 a4 = *(const float4*)&a_lds[kk][ty * 4];
      float4 b4 = *(const float4*)&b_lds[kk][tx * 4];
      acc[0][0] += a4.x * b4.x; acc[0][1] += a4.x * b4.y; acc[0][2] += a4.x * b4.z; acc[0][3] += a4.x * b4.w;
      acc[1][0] += a4.y * b4.x; acc[1][1] += a4.y * b4.y; acc[1][2] += a4.y * b4.z; acc[1][3] += a4.y * b4.w;
      acc[2][0] += a4.z * b4.x; acc[2][1] += a4.z * b4.y; acc[2][2] += a4.z * b4.z; acc[2][3] += a4.z * b4.w;
      acc[3][0] += a4.w * b4.x; acc[3][1] += a4.w * b4.y; acc[3][2] += a4.w * b4.z; acc[3][3] += a4.w * b4.w;
    }
    __syncthreads();
  }
  float4 bias4 = *(const float4*)&bias[n0 + tx * 4];
#pragma unroll
  for (int i = 0; i < 4; ++i) {
    int m = m0 + ty * 4 + i;
    float4 v;
    v.x = acc[i][0] + bias4.x;
    v.y = acc[i][1] + bias4.y;
    v.z = acc[i][2] + bias4.z;
    v.w = acc[i][3] + bias4.w;
    if (RELU) {
      v.x = fmaxf(v.x, 0.f); v.y = fmaxf(v.y, 0.f);
      v.z = fmaxf(v.z, 0.f); v.w = fmaxf(v.w, 0.f);
    }
    *(float4*)&out[(size_t)m * N + n0 + tx * 4] = v;
  }
}

// ---------------- layernorm: out = LN(xa + xb) * g + b, one wave per row -----
__global__ __launch_bounds__(256) void k_ln(const float* __restrict__ xa,
                                            const float* __restrict__ xb,
                                            const float* __restrict__ g,
                                            const float* __restrict__ bb,
                                            float* __restrict__ out) {
  int wid = (blockIdx.x * 256 + threadIdx.x) >> 6;  // row
  int lane = threadIdx.x & 63;
  float4 va = *(const float4*)(xa + (size_t)wid * C_ + lane * 4);
  float4 vb = *(const float4*)(xb + (size_t)wid * C_ + lane * 4);
  float x0 = va.x + vb.x, x1 = va.y + vb.y, x2 = va.z + vb.z, x3 = va.w + vb.w;
  float s = x0 + x1 + x2 + x3;
#pragma unroll
  for (int off = 32; off >= 1; off >>= 1) s += __shfl_xor(s, off);
  float mean = s * (1.f / C_);
  float d0 = x0 - mean, d1 = x1 - mean, d2 = x2 - mean, d3 = x3 - mean;
  float v = d0 * d0 + d1 * d1 + d2 * d2 + d3 * d3;
#pragma unroll
  for (int off = 32; off >= 1; off >>= 1) v += __shfl_xor(v, off);
  float inv = 1.f / sqrtf(v * (1.f / C_) + EPS_);
  float4 g4 = *(const float4*)(g + lane * 4);
  float4 b4 = *(const float4*)(bb + lane * 4);
  float4 o;
  o.x = d0 * inv * g4.x + b4.x;
  o.y = d1 * inv * g4.y + b4.y;
  o.z = d2 * inv * g4.z + b4.z;
  o.w = d3 * inv * g4.w + b4.w;
  *(float4*)(out + (size_t)wid * C_ + lane * 4) = o;
}

extern "C" void kernel_launch(void* const* d_in, const int* in_sizes, int n_in,
                              void* d_out, int out_size, void* d_ws, size_t ws_size,
                              hipStream_t stream) {
  const float* query     = (const float*)d_in[0];
  const float* key       = (const float*)d_in[1];
  const float* query_pos = (const float*)d_in[2];
  const float* key_pos   = (const float*)d_in[3];
  const float* q_w = (const float*)d_in[4];  const float* q_b = (const float*)d_in[5];
  const float* k_w = (const float*)d_in[6];  const float* k_b = (const float*)d_in[7];
  const float* v_w = (const float*)d_in[8];  const float* v_b = (const float*)d_in[9];
  const float* o_w = (const float*)d_in[10]; const float* o_b = (const float*)d_in[11];
  const float* lin1_w = (const float*)d_in[12]; const float* lin1_b = (const float*)d_in[13];
  const float* lin2_w = (const float*)d_in[14]; const float* lin2_b = (const float*)d_in[15];
  const float* n1_g = (const float*)d_in[16]; const float* n1_b = (const float*)d_in[17];
  const float* n2_g = (const float*)d_in[18]; const float* n2_b = (const float*)d_in[19];
  const float* qpe_w = (const float*)d_in[20]; const float* qpe_b = (const float*)d_in[21];
  const float* kpe_w = (const float*)d_in[22]; const float* kpe_b = (const float*)d_in[23];
  float* out = (float*)d_out;

  const size_t BQc = (size_t)BQ_ * C_;
  float* w = (float*)d_ws;
  size_t o = 0;
  float* keyT  = w + o; o += (size_t)B_ * NK_ * C_;  // 33.5 MB
  float* qtok  = w + o; o += BQc;
  float* qin   = w + o; o += BQc;
  float* qh    = w + o; o += BQc;
  float* aob   = w + o; o += BQc;
  float* attno = w + o; o += BQc;
  float* x1    = w + o; o += BQc;
  float* ff1   = w + o; o += (size_t)BQ_ * FF_;      // 67 MB
  float* qwT   = w + o; o += (size_t)C_ * C_;
  float* kwT   = w + o; o += (size_t)C_ * C_;
  float* vwT   = w + o; o += (size_t)C_ * C_;
  float* owT   = w + o; o += (size_t)C_ * C_;
  float* l1T   = w + o; o += (size_t)C_ * FF_;
  float* l2T   = w + o; o += (size_t)FF_ * C_;
  int*   idxb  = (int*)(w + o); o += (size_t)BQ_ * S_;
  int*   maskb = (int*)(w + o); o += (size_t)BQ_ * S_;
  // lifetime overlays (qin dead after q-proj GEMM; qh dead after k_attn)
  float* x2   = qin;
  float* ff2o = qh;

  dim3 tb(32, 8);
  // layout transposes
  k_transpose<<<dim3(NK_ / 32, C_ / 32, B_), tb, 0, stream>>>(key, keyT, C_, NK_);
  k_transpose<<<dim3(NQ_ / 32, C_ / 32, B_), tb, 0, stream>>>(query, qtok, C_, NQ_);
  k_transpose<<<dim3(C_ / 32, C_ / 32, 1), tb, 0, stream>>>(q_w, qwT, C_, C_);
  k_transpose<<<dim3(C_ / 32, C_ / 32, 1), tb, 0, stream>>>(k_w, kwT, C_, C_);
  k_transpose<<<dim3(C_ / 32, C_ / 32, 1), tb, 0, stream>>>(v_w, vwT, C_, C_);
  k_transpose<<<dim3(C_ / 32, C_ / 32, 1), tb, 0, stream>>>(o_w, owT, C_, C_);
  k_transpose<<<dim3(C_ / 32, FF_ / 32, 1), tb, 0, stream>>>(lin1_w, l1T, FF_, C_);
  k_transpose<<<dim3(FF_ / 32, C_ / 32, 1), tb, 0, stream>>>(lin2_w, l2T, C_, FF_);
  // qin = qtok + qpe
  k_qin<<<BQ_ * C_ / 256, 256, 0, stream>>>(qtok, query_pos, qpe_w, qpe_b, qin);
  // box query
  k_boxq<<<BQ_ / 4, 256, 0, stream>>>(key_pos, query_pos, idxb, maskb);
  // qh = qin @ q_w.T + q_b
  k_gemm<0><<<dim3(C_ / 64, BQ_ / 64), 256, 0, stream>>>(qin, qwT, q_b, qh, BQ_, C_, C_);
  // fused gather/kpe/kh/vh/attention -> ao
  k_attn<<<BQ_, 256, 0, stream>>>(keyT, key_pos, query_pos, idxb, maskb, qh,
                                  kwT, k_b, vwT, v_b, kpe_w, kpe_b, aob);
  // o projection
  k_gemm<0><<<dim3(C_ / 64, BQ_ / 64), 256, 0, stream>>>(aob, owT, o_b, attno, BQ_, C_, C_);
  // x1 = LN(qtok + attno)
  k_ln<<<BQ_ / 4, 256, 0, stream>>>(qtok, attno, n1_g, n1_b, x1);
  // ff1 = relu(x1 @ lin1.T + b)
  k_gemm<1><<<dim3(FF_ / 64, BQ_ / 64), 256, 0, stream>>>(x1, l1T, lin1_b, ff1, BQ_, FF_, C_);
  // ff2 = ff1 @ lin2.T + b
  k_gemm<0><<<dim3(C_ / 64, BQ_ / 64), 256, 0, stream>>>(ff1, l2T, lin2_b, ff2o, BQ_, C_, FF_);
  // x2 = LN(x1 + ff2)
  k_ln<<<BQ_ / 4, 256, 0, stream>>>(x1, ff2o, n2_g, n2_b, x2);
  // out (B, C, NQ) = transpose(x2 as (B, NQ, C))
  k_transpose<<<dim3(C_ / 32, NQ_ / 32, B_), tb, 0, stream>>>(x2, out, NQ_, C_);
}

// Round 3
// 435.179 us; speedup vs baseline: 2.4635x; 2.4635x over previous
//
#include <hip/hip_runtime.h>
#include <cstdint>

#define B_   8
#define C_   256
#define NQ_  1024
#define NK_  4096
#define S_   16
#define H_   8
#define FF_  2048
#define DH_  32
#define BQ_  (B_*NQ_)
#define EPS_ 1e-5f

typedef __bf16 bf16x8 __attribute__((ext_vector_type(8)));
typedef float  f32x4  __attribute__((ext_vector_type(4)));

// ---------------- fp32 transpose of last two dims ----------------
// in: (Z, RI, CJ) -> out: (Z, CJ, RI).  grid: (CJ/32, RI/32, Z), block (32,8)
__global__ __launch_bounds__(256) void k_transpose(const float* __restrict__ in,
                                                   float* __restrict__ out,
                                                   int RI, int CJ) {
  __shared__ float t[32][33];
  int z = blockIdx.z;
  int j0 = blockIdx.x * 32, i0 = blockIdx.y * 32;
  const float* inz = in + (size_t)z * RI * CJ;
  float* outz = out + (size_t)z * RI * CJ;
  int tx = threadIdx.x, ty = threadIdx.y;
#pragma unroll
  for (int r = 0; r < 32; r += 8)
    t[ty + r][tx] = inz[(size_t)(i0 + ty + r) * CJ + (j0 + tx)];
  __syncthreads();
#pragma unroll
  for (int r = 0; r < 32; r += 8)
    outz[(size_t)(j0 + ty + r) * RI + (i0 + tx)] = t[tx][ty + r];
}

// ---------------- fp32 -> bf16 transpose (for key -> keyTb) ----------------
__global__ __launch_bounds__(256) void k_transb(const float* __restrict__ in,
                                                __bf16* __restrict__ out,
                                                int RI, int CJ) {
  __shared__ float t[32][33];
  int z = blockIdx.z;
  int j0 = blockIdx.x * 32, i0 = blockIdx.y * 32;
  const float* inz = in + (size_t)z * RI * CJ;
  __bf16* outz = out + (size_t)z * RI * CJ;
  int tx = threadIdx.x, ty = threadIdx.y;
#pragma unroll
  for (int r = 0; r < 32; r += 8)
    t[ty + r][tx] = inz[(size_t)(i0 + ty + r) * CJ + (j0 + tx)];
  __syncthreads();
#pragma unroll
  for (int r = 0; r < 32; r += 8)
    outz[(size_t)(j0 + ty + r) * RI + (i0 + tx)] = (__bf16)t[tx][ty + r];
}

// ---------------- fp32 -> bf16 convert (4 elems/thread) ----------------
__global__ __launch_bounds__(256) void k_cvt(const float* __restrict__ in,
                                             __bf16* __restrict__ out, int n4) {
  int i = blockIdx.x * 256 + threadIdx.x;
  if (i >= n4) return;
  float4 v = *(const float4*)(in + (size_t)i * 4);
  __bf16* o = out + (size_t)i * 4;
  o[0] = (__bf16)v.x; o[1] = (__bf16)v.y; o[2] = (__bf16)v.z; o[3] = (__bf16)v.w;
}

// ---- P[n] = (kpe_w[:,0..2] dot w[n,:], kpe_b dot w[n,:] + wb[n]) -----------
// one block, 256 threads
__global__ __launch_bounds__(256) void k_pproj(const float* __restrict__ w,
                                               const float* __restrict__ wb,
                                               const float* __restrict__ kpw,
                                               const float* __restrict__ kpb,
                                               float4* __restrict__ P) {
  int n = threadIdx.x;
  const float* wr = w + (size_t)n * C_;
  float p0 = 0.f, p1 = 0.f, p2 = 0.f, pb = 0.f;
  for (int k = 0; k < C_; ++k) {
    float wv = wr[k];
    p0 += kpw[k * 3 + 0] * wv;
    p1 += kpw[k * 3 + 1] * wv;
    p2 += kpw[k * 3 + 2] * wv;
    pb += kpb[k] * wv;
  }
  P[n] = make_float4(p0, p1, p2, pb + wb[n]);
}

// ---------------- qin(bf16) = qtok + query_pos @ qpe_w.T + qpe_b ----------
__global__ __launch_bounds__(256) void k_qin(const float* __restrict__ qtok,
                                             const float* __restrict__ query_pos,
                                             const float* __restrict__ qpe_w,
                                             const float* __restrict__ qpe_b,
                                             __bf16* __restrict__ qinb) {
  int i = blockIdx.x * 256 + threadIdx.x;
  int bq = i >> 8, c = i & 255;
  const float* qp = query_pos + (size_t)bq * 6;
  const float* w  = qpe_w + (size_t)c * 6;
  float acc = qpe_b[c];
#pragma unroll
  for (int j = 0; j < 6; ++j) acc += qp[j] * w[j];
  qinb[i] = (__bf16)(qtok[i] + acc);
}

// ---------------- box query: one wave per query token ----------------
__global__ __launch_bounds__(256) void k_boxq(const float* __restrict__ key_pos,
                                              const float* __restrict__ query_pos,
                                              int* __restrict__ idxo,
                                              int* __restrict__ masko) {
  __shared__ float kp[NK_ * 3];  // 48 KB
  int b = (blockIdx.x * 4) >> 10;  // / NQ_
  const float* kpg = key_pos + (size_t)b * NK_ * 3;
  for (int t = threadIdx.x; t < NK_ * 3; t += 256) kp[t] = kpg[t];
  __syncthreads();
  int lane = threadIdx.x & 63;
  int q = blockIdx.x * 4 + (threadIdx.x >> 6);  // global (b*NQ+nq)
  const float* qp = query_pos + (size_t)q * 6;
  float cx = qp[0], cy = qp[1], cz = qp[2];
  float hx = 0.5f * qp[3], hy = 0.5f * qp[4], hz = 0.5f * qp[5];
  int* iq = idxo + (size_t)q * S_;
  int found = 0;
  for (int ch = 0; ch < NK_ / 64; ++ch) {
    int k = ch * 64 + lane;
    float dx = fabsf(kp[k * 3 + 0] - cx);
    float dy = fabsf(kp[k * 3 + 1] - cy);
    float dz = fabsf(kp[k * 3 + 2] - cz);
    bool inside = (dx <= hx) && (dy <= hy) && (dz <= hz);
    unsigned long long bal = __ballot(inside);
    if (inside) {
      int slot = found + __popcll(bal & ((1ull << lane) - 1ull));
      if (slot < S_) iq[slot] = k;
    }
    found += __popcll(bal);
    if (found >= S_) break;
  }
  if (found > S_) found = S_;
  if (lane < S_) {
    int m = (lane < found) ? 0 : 1;
    if (lane >= found) iq[lane] = 0;
    if (lane == 0) m = 0;
    masko[(size_t)q * S_ + lane] = m;
  }
}

// ---------------- bf16 MFMA GEMM: out = A(M,K) @ Wn(N,K)^T + bias ----------
// 128x128 block tile, BK=64, 256 threads = 4 waves in 2x2, 4x4 mfma tiles/wave
template <int RELU, int OUT_BF16>
__global__ __launch_bounds__(256) void k_gemm_bf16(
    const __bf16* __restrict__ A,   // (M, K) row-major
    const __bf16* __restrict__ Wn,  // (N, K) row-major
    const float* __restrict__ bias, // (N)
    void* __restrict__ outp, int M, int N, int K) {
  __shared__ __bf16 As[128][72];  // +8 pad: frag-read lanes spread banks
  __shared__ __bf16 Bs[128][72];
  int n0 = blockIdx.x * 128, m0 = blockIdx.y * 128;
  int t = threadIdx.x;
  int lane = t & 63, w = t >> 6;
  int lane16 = lane & 15, quad = lane >> 4;
  int wm = (w & 1) * 64, wn = (w >> 1) * 64;

  f32x4 acc[4][4];
#pragma unroll
  for (int i = 0; i < 4; ++i)
#pragma unroll
    for (int j = 0; j < 4; ++j) acc[i][j] = (f32x4){0.f, 0.f, 0.f, 0.f};

  for (int k0 = 0; k0 < K; k0 += 64) {
#pragma unroll
    for (int i = 0; i < 4; ++i) {
      int ii = i * 256 + t;
      int m = ii >> 3, kc = (ii & 7) * 8;
      *(bf16x8*)&As[m][kc] = *(const bf16x8*)&A[(size_t)(m0 + m) * K + k0 + kc];
      *(bf16x8*)&Bs[m][kc] = *(const bf16x8*)&Wn[(size_t)(n0 + m) * K + k0 + kc];
    }
    __syncthreads();
#pragma unroll
    for (int kk = 0; kk < 64; kk += 32) {
      bf16x8 af[4], bfr[4];
#pragma unroll
      for (int i = 0; i < 4; ++i)
        af[i] = *(const bf16x8*)&As[wm + i * 16 + lane16][kk + quad * 8];
#pragma unroll
      for (int j = 0; j < 4; ++j)
        bfr[j] = *(const bf16x8*)&Bs[wn + j * 16 + lane16][kk + quad * 8];
#pragma unroll
      for (int i = 0; i < 4; ++i)
#pragma unroll
        for (int j = 0; j < 4; ++j)
          acc[i][j] = __builtin_amdgcn_mfma_f32_16x16x32_bf16(af[i], bfr[j], acc[i][j], 0, 0, 0);
    }
    __syncthreads();
  }

#pragma unroll
  for (int j = 0; j < 4; ++j) {
    int col = n0 + wn + j * 16 + lane16;
    float bv = bias[col];
#pragma unroll
    for (int i = 0; i < 4; ++i) {
#pragma unroll
      for (int r = 0; r < 4; ++r) {
        int row = m0 + wm + i * 16 + quad * 4 + r;
        float v = acc[i][j][r] + bv;
        if (RELU) v = fmaxf(v, 0.f);
        if (OUT_BF16)
          ((__bf16*)outp)[(size_t)row * N + col] = (__bf16)v;
        else
          ((float*)outp)[(size_t)row * N + col] = v;
      }
    }
  }
}

// ------ fused-gather kv GEMM: out(r,n) = keyTb[srow_r,:] @ Wn(n,:)^T
//                                         + gx_r . P[n].xyz + P[n].w
// r = bq*16+s over M=BQ*S rows; N=K=256. grid (2, M/128). ----------------
__global__ __launch_bounds__(256) void k_kvgemm(
    const __bf16* __restrict__ keyTb,     // (B, NK, C) bf16
    const float* __restrict__ key_pos,    // (B, NK, 3)
    const float* __restrict__ query_pos,  // (BQ, 6)
    const int* __restrict__ idx,          // (BQ, S)
    const __bf16* __restrict__ Wn,        // (C, C) bf16
    const float4* __restrict__ P,         // (C) folded kpe projection + bias
    __bf16* __restrict__ outp) {          // (BQ*S, C)
  __shared__ __bf16 As[128][72];
  __shared__ __bf16 Bs[128][72];
  __shared__ float4 sgx[128];
  __shared__ int    srow[128];
  __shared__ float4 Pl[C_];
  int n0 = blockIdx.x * 128, m0 = blockIdx.y * 128;
  int t = threadIdx.x;
  int lane = t & 63, w = t >> 6;
  int lane16 = lane & 15, quad = lane >> 4;
  int wm = (w & 1) * 64, wn = (w >> 1) * 64;

  Pl[t] = P[t];
  if (t < 128) {
    int r = m0 + t;
    int bq = r >> 4, s = r & 15;
    int b = bq >> 10;
    int k = idx[(size_t)bq * S_ + s];
    srow[t] = b * NK_ + k;
    const float* kpp = key_pos + ((size_t)b * NK_ + k) * 3;
    const float* qp  = query_pos + (size_t)bq * 6;
    sgx[t] = make_float4(kpp[0] - qp[0], kpp[1] - qp[1], kpp[2] - qp[2], 0.f);
  }
  __syncthreads();

  f32x4 acc[4][4];
#pragma unroll
  for (int i = 0; i < 4; ++i)
#pragma unroll
    for (int j = 0; j < 4; ++j) acc[i][j] = (f32x4){0.f, 0.f, 0.f, 0.f};

  for (int k0 = 0; k0 < C_; k0 += 64) {
#pragma unroll
    for (int i = 0; i < 4; ++i) {
      int ii = i * 256 + t;
      int m = ii >> 3, kc = (ii & 7) * 8;
      *(bf16x8*)&As[m][kc] = *(const bf16x8*)&keyTb[(size_t)srow[m] * C_ + k0 + kc];
      *(bf16x8*)&Bs[m][kc] = *(const bf16x8*)&Wn[(size_t)(n0 + m) * C_ + k0 + kc];
    }
    __syncthreads();
#pragma unroll
    for (int kk = 0; kk < 64; kk += 32) {
      bf16x8 af[4], bfr[4];
#pragma unroll
      for (int i = 0; i < 4; ++i)
        af[i] = *(const bf16x8*)&As[wm + i * 16 + lane16][kk + quad * 8];
#pragma unroll
      for (int j = 0; j < 4; ++j)
        bfr[j] = *(const bf16x8*)&Bs[wn + j * 16 + lane16][kk + quad * 8];
#pragma unroll
      for (int i = 0; i < 4; ++i)
#pragma unroll
        for (int j = 0; j < 4; ++j)
          acc[i][j] = __builtin_amdgcn_mfma_f32_16x16x32_bf16(af[i], bfr[j], acc[i][j], 0, 0, 0);
    }
    __syncthreads();
  }

#pragma unroll
  for (int j = 0; j < 4; ++j) {
    int col = n0 + wn + j * 16 + lane16;
    float4 p = Pl[col];
#pragma unroll
    for (int i = 0; i < 4; ++i) {
#pragma unroll
      for (int r = 0; r < 4; ++r) {
        int rl = wm + i * 16 + quad * 4 + r;
        float4 g = sgx[rl];
        float v = acc[i][j][r] + g.x * p.x + g.y * p.y + g.z * p.z + p.w;
        outp[(size_t)(m0 + rl) * C_ + col] = (__bf16)v;
      }
    }
  }
}

// ---------------- scores + softmax -> attw (BQ, H, S) ----------------
__global__ __launch_bounds__(256) void k_scores(const __bf16* __restrict__ qhb,
                                                const __bf16* __restrict__ khbuf,
                                                const int* __restrict__ maskb,
                                                float* __restrict__ attw) {
  __shared__ float qrow[C_];
  __shared__ float sc[H_ * S_];
  __shared__ int smask[S_];
  int bq = blockIdx.x;
  int t = threadIdx.x;
  qrow[t] = (float)qhb[(size_t)bq * C_ + t];
  if (t < S_) smask[t] = maskb[(size_t)bq * S_ + t];
  __syncthreads();
  if (t < H_ * S_) {
    int h = t >> 4, s = t & (S_ - 1);
    const __bf16* kr = khbuf + ((size_t)bq * S_ + s) * C_ + h * DH_;
    float d = 0.f;
#pragma unroll
    for (int k = 0; k < DH_; ++k) d += qrow[h * DH_ + k] * (float)kr[k];
    d *= 0.17677669529663687f;
    if (smask[s]) d = -1e30f;
    sc[t] = d;
  }
  __syncthreads();
  if (t < H_) {
    float mx = -3.4e38f;
#pragma unroll
    for (int s = 0; s < S_; ++s) mx = fmaxf(mx, sc[t * S_ + s]);
    float e[S_], sum = 0.f;
#pragma unroll
    for (int s = 0; s < S_; ++s) { e[s] = expf(sc[t * S_ + s] - mx); sum += e[s]; }
    float inv = 1.f / sum;
#pragma unroll
    for (int s = 0; s < S_; ++s)
      attw[(size_t)bq * H_ * S_ + t * S_ + s] = e[s] * inv;
  }
}

// ---------------- PV: ao = attn @ vh ----------------
__global__ __launch_bounds__(256) void k_pv(const __bf16* __restrict__ vhbuf,
                                            const float* __restrict__ attw,
                                            __bf16* __restrict__ aob) {
  __shared__ float pw[H_ * S_];
  int bq = blockIdx.x;
  int t = threadIdx.x;
  if (t < H_ * S_) pw[t] = attw[(size_t)bq * H_ * S_ + t];
  __syncthreads();
  int h = t >> 5;  // DH_=32
  float a = 0.f;
#pragma unroll
  for (int s = 0; s < S_; ++s)
    a += pw[h * S_ + s] * (float)vhbuf[((size_t)bq * S_ + s) * C_ + t];
  aob[(size_t)bq * C_ + t] = (__bf16)a;
}

// ---------------- layernorm: out = LN(xa + xb)*g + b; optional bf16 copy ----
template <int WB>
__global__ __launch_bounds__(256) void k_ln(const float* __restrict__ xa,
                                            const float* __restrict__ xb,
                                            const float* __restrict__ g,
                                            const float* __restrict__ bb,
                                            float* __restrict__ outf,
                                            __bf16* __restrict__ outb) {
  int wid = (blockIdx.x * 256 + threadIdx.x) >> 6;
  int lane = threadIdx.x & 63;
  float4 va = *(const float4*)(xa + (size_t)wid * C_ + lane * 4);
  float4 vb = *(const float4*)(xb + (size_t)wid * C_ + lane * 4);
  float x0 = va.x + vb.x, x1 = va.y + vb.y, x2 = va.z + vb.z, x3 = va.w + vb.w;
  float s = x0 + x1 + x2 + x3;
#pragma unroll
  for (int off = 32; off >= 1; off >>= 1) s += __shfl_xor(s, off);
  float mean = s * (1.f / C_);
  float d0 = x0 - mean, d1 = x1 - mean, d2 = x2 - mean, d3 = x3 - mean;
  float v = d0 * d0 + d1 * d1 + d2 * d2 + d3 * d3;
#pragma unroll
  for (int off = 32; off >= 1; off >>= 1) v += __shfl_xor(v, off);
  float inv = 1.f / sqrtf(v * (1.f / C_) + EPS_);
  float4 g4 = *(const float4*)(g + lane * 4);
  float4 b4 = *(const float4*)(bb + lane * 4);
  float4 o;
  o.x = d0 * inv * g4.x + b4.x;
  o.y = d1 * inv * g4.y + b4.y;
  o.z = d2 * inv * g4.z + b4.z;
  o.w = d3 * inv * g4.w + b4.w;
  *(float4*)(outf + (size_t)wid * C_ + lane * 4) = o;
  if (WB) {
    __bf16* ob = outb + (size_t)wid * C_ + lane * 4;
    ob[0] = (__bf16)o.x; ob[1] = (__bf16)o.y; ob[2] = (__bf16)o.z; ob[3] = (__bf16)o.w;
  }
}

extern "C" void kernel_launch(void* const* d_in, const int* in_sizes, int n_in,
                              void* d_out, int out_size, void* d_ws, size_t ws_size,
                              hipStream_t stream) {
  const float* query     = (const float*)d_in[0];
  const float* key       = (const float*)d_in[1];
  const float* query_pos = (const float*)d_in[2];
  const float* key_pos   = (const float*)d_in[3];
  const float* q_w = (const float*)d_in[4];  const float* q_b = (const float*)d_in[5];
  const float* k_w = (const float*)d_in[6];  const float* k_b = (const float*)d_in[7];
  const float* v_w = (const float*)d_in[8];  const float* v_b = (const float*)d_in[9];
  const float* o_w = (const float*)d_in[10]; const float* o_b = (const float*)d_in[11];
  const float* lin1_w = (const float*)d_in[12]; const float* lin1_b = (const float*)d_in[13];
  const float* lin2_w = (const float*)d_in[14]; const float* lin2_b = (const float*)d_in[15];
  const float* n1_g = (const float*)d_in[16]; const float* n1_b = (const float*)d_in[17];
  const float* n2_g = (const float*)d_in[18]; const float* n2_b = (const float*)d_in[19];
  const float* qpe_w = (const float*)d_in[20]; const float* qpe_b = (const float*)d_in[21];
  const float* kpe_w = (const float*)d_in[22]; const float* kpe_b = (const float*)d_in[23];
  float* out = (float*)d_out;

  const size_t BQc = (size_t)BQ_ * C_;
  float* w = (float*)d_ws;
  size_t o = 0;
  // ---- workspace carve: ~142 MB total (R0's 157 MB carve passed) ----
  __bf16* keyTb = (__bf16*)(w + o); o += (size_t)B_ * NK_ * C_ / 2;  // 16.8 MB
  float* qtok  = w + o; o += BQc;                                    //  8.4 MB
  float* x1    = w + o; o += BQc;
  float* attno = w + o; o += BQc;                                    // reused as ff2o
  float* x2    = w + o; o += BQc;
  __bf16* khv  = (__bf16*)(w + o); o += BQc * S_ / 2;                // 67 MB: kh, then vh, then ff1
  float* attw  = w + o; o += (size_t)BQ_ * H_ * S_;                  //  4.2 MB
  __bf16* qinb = (__bf16*)(w + o); o += BQc / 2;
  __bf16* qhb  = (__bf16*)(w + o); o += BQc / 2;
  __bf16* aob  = (__bf16*)(w + o); o += BQc / 2;
  __bf16* x1b  = (__bf16*)(w + o); o += BQc / 2;
  __bf16* qwb  = (__bf16*)(w + o); o += (size_t)C_ * C_ / 2;
  __bf16* kwb  = (__bf16*)(w + o); o += (size_t)C_ * C_ / 2;
  __bf16* vwb  = (__bf16*)(w + o); o += (size_t)C_ * C_ / 2;
  __bf16* owb  = (__bf16*)(w + o); o += (size_t)C_ * C_ / 2;
  __bf16* l1b  = (__bf16*)(w + o); o += (size_t)C_ * FF_ / 2;
  __bf16* l2b  = (__bf16*)(w + o); o += (size_t)C_ * FF_ / 2;
  float4* Pk   = (float4*)(w + o); o += C_ * 4;
  float4* Pv   = (float4*)(w + o); o += C_ * 4;
  int* idxb  = (int*)(w + o); o += (size_t)BQ_ * S_;
  int* maskb = (int*)(w + o); o += (size_t)BQ_ * S_;
  __bf16* ff1b = khv;       // kh/vh dead after k_pv
  float* ff2o  = attno;     // attno dead after LN1

  dim3 tb(32, 8);
  // layout transforms
  k_transb<<<dim3(NK_ / 32, C_ / 32, B_), tb, 0, stream>>>(key, keyTb, C_, NK_);
  k_transpose<<<dim3(NQ_ / 32, C_ / 32, B_), tb, 0, stream>>>(query, qtok, C_, NQ_);
  // weight casts (all (N,K) row-major already — MFMA B-operand layout)
  k_cvt<<<C_ * C_ / 4 / 256, 256, 0, stream>>>(q_w, qwb, C_ * C_ / 4);
  k_cvt<<<C_ * C_ / 4 / 256, 256, 0, stream>>>(k_w, kwb, C_ * C_ / 4);
  k_cvt<<<C_ * C_ / 4 / 256, 256, 0, stream>>>(v_w, vwb, C_ * C_ / 4);
  k_cvt<<<C_ * C_ / 4 / 256, 256, 0, stream>>>(o_w, owb, C_ * C_ / 4);
  k_cvt<<<C_ * FF_ / 4 / 256, 256, 0, stream>>>(lin1_w, l1b, C_ * FF_ / 4);
  k_cvt<<<C_ * FF_ / 4 / 256, 256, 0, stream>>>(lin2_w, l2b, C_ * FF_ / 4);
  // folded kpe projections: Pk = kpe through k_w, Pv = kpe through v_w
  k_pproj<<<1, 256, 0, stream>>>(k_w, k_b, kpe_w, kpe_b, Pk);
  k_pproj<<<1, 256, 0, stream>>>(v_w, v_b, kpe_w, kpe_b, Pv);
  // qin(bf16) = qtok + qpe
  k_qin<<<BQ_ * C_ / 256, 256, 0, stream>>>(qtok, query_pos, qpe_w, qpe_b, qinb);
  // box query
  k_boxq<<<BQ_ / 4, 256, 0, stream>>>(key_pos, query_pos, idxb, maskb);
  // qh = qin @ q_w.T + q_b
  k_gemm_bf16<0, 1><<<dim3(C_ / 128, BQ_ / 128), 256, 0, stream>>>(qinb, qwb, q_b, qhb, BQ_, C_, C_);
  // kh = gather(key) @ k_w.T + folded kpe  -> khv
  k_kvgemm<<<dim3(C_ / 128, BQ_ * S_ / 128), 256, 0, stream>>>(
      keyTb, key_pos, query_pos, idxb, kwb, Pk, khv);
  // scores + softmax
  k_scores<<<BQ_, 256, 0, stream>>>(qhb, khv, maskb, attw);
  // vh = gather(key) @ v_w.T + folded kpe  -> khv (overwrite kh)
  k_kvgemm<<<dim3(C_ / 128, BQ_ * S_ / 128), 256, 0, stream>>>(
      keyTb, key_pos, query_pos, idxb, vwb, Pv, khv);
  // ao = attn @ vh
  k_pv<<<BQ_, 256, 0, stream>>>(khv, attw, aob);
  // o projection (fp32 out)
  k_gemm_bf16<0, 0><<<dim3(C_ / 128, BQ_ / 128), 256, 0, stream>>>(aob, owb, o_b, attno, BQ_, C_, C_);
  // x1 = LN(qtok + attno), plus bf16 copy
  k_ln<1><<<BQ_ / 4, 256, 0, stream>>>(qtok, attno, n1_g, n1_b, x1, x1b);
  // ff1(bf16) = relu(x1 @ lin1.T + b)   [overlays khv]
  k_gemm_bf16<1, 1><<<dim3(FF_ / 128, BQ_ / 128), 256, 0, stream>>>(x1b, l1b, lin1_b, ff1b, BQ_, FF_, C_);
  // ff2(fp32) = ff1 @ lin2.T + b        [overlays attno]
  k_gemm_bf16<0, 0><<<dim3(C_ / 128, BQ_ / 128), 256, 0, stream>>>(ff1b, l2b, lin2_b, ff2o, BQ_, C_, FF_);
  // x2 = LN(x1 + ff2)
  k_ln<0><<<BQ_ / 4, 256, 0, stream>>>(x1, ff2o, n2_g, n2_b, x2, nullptr);
  // out (B, C, NQ) = transpose(x2 as (B, NQ, C))
  k_transpose<<<dim3(C_ / 32, NQ_ / 32, B_), tb, 0, stream>>>(x2, out, NQ_, C_);
}

// Round 4
// 361.324 us; speedup vs baseline: 2.9670x; 1.2044x over previous
//
#include <hip/hip_runtime.h>
#include <cstdint>

#define B_   8
#define C_   256
#define NQ_  1024
#define NK_  4096
#define S_   16
#define H_   8
#define FF_  2048
#define DH_  32
#define BQ_  (B_*NQ_)
#define EPS_ 1e-5f

typedef __bf16 bf16x8 __attribute__((ext_vector_type(8)));
typedef float  f32x4  __attribute__((ext_vector_type(4)));

// ---------------- fp32 transpose of last two dims ----------------
__global__ __launch_bounds__(256) void k_transpose(const float* __restrict__ in,
                                                   float* __restrict__ out,
                                                   int RI, int CJ) {
  __shared__ float t[32][33];
  int z = blockIdx.z;
  int j0 = blockIdx.x * 32, i0 = blockIdx.y * 32;
  const float* inz = in + (size_t)z * RI * CJ;
  float* outz = out + (size_t)z * RI * CJ;
  int tx = threadIdx.x, ty = threadIdx.y;
#pragma unroll
  for (int r = 0; r < 32; r += 8)
    t[ty + r][tx] = inz[(size_t)(i0 + ty + r) * CJ + (j0 + tx)];
  __syncthreads();
#pragma unroll
  for (int r = 0; r < 32; r += 8)
    outz[(size_t)(j0 + ty + r) * RI + (i0 + tx)] = t[tx][ty + r];
}

// ---------------- fp32 -> bf16 transpose ----------------
__global__ __launch_bounds__(256) void k_transb(const float* __restrict__ in,
                                                __bf16* __restrict__ out,
                                                int RI, int CJ) {
  __shared__ float t[32][33];
  int z = blockIdx.z;
  int j0 = blockIdx.x * 32, i0 = blockIdx.y * 32;
  const float* inz = in + (size_t)z * RI * CJ;
  __bf16* outz = out + (size_t)z * RI * CJ;
  int tx = threadIdx.x, ty = threadIdx.y;
#pragma unroll
  for (int r = 0; r < 32; r += 8)
    t[ty + r][tx] = inz[(size_t)(i0 + ty + r) * CJ + (j0 + tx)];
  __syncthreads();
#pragma unroll
  for (int r = 0; r < 32; r += 8)
    outz[(size_t)(j0 + ty + r) * RI + (i0 + tx)] = (__bf16)t[tx][ty + r];
}

// ---------------- fp32 -> bf16 convert ----------------
__global__ __launch_bounds__(256) void k_cvt(const float* __restrict__ in,
                                             __bf16* __restrict__ out, int n4) {
  int i = blockIdx.x * 256 + threadIdx.x;
  if (i >= n4) return;
  float4 v = *(const float4*)(in + (size_t)i * 4);
  __bf16* o = out + (size_t)i * 4;
  o[0] = (__bf16)v.x; o[1] = (__bf16)v.y; o[2] = (__bf16)v.z; o[3] = (__bf16)v.w;
}

// ---- P[n] = (kpe_w[:,0..2] dot w[n,:], kpe_b dot w[n,:] + wb[n]) -----------
__global__ __launch_bounds__(256) void k_pproj(const float* __restrict__ w,
                                               const float* __restrict__ wb,
                                               const float* __restrict__ kpw,
                                               const float* __restrict__ kpb,
                                               float4* __restrict__ P) {
  int n = threadIdx.x;
  const float* wr = w + (size_t)n * C_;
  float p0 = 0.f, p1 = 0.f, p2 = 0.f, pb = 0.f;
  for (int k = 0; k < C_; ++k) {
    float wv = wr[k];
    p0 += kpw[k * 3 + 0] * wv;
    p1 += kpw[k * 3 + 1] * wv;
    p2 += kpw[k * 3 + 2] * wv;
    pb += kpb[k] * wv;
  }
  P[n] = make_float4(p0, p1, p2, pb + wb[n]);
}

// ---------------- qin(bf16) = qtok + query_pos @ qpe_w.T + qpe_b ----------
__global__ __launch_bounds__(256) void k_qin(const float* __restrict__ qtok,
                                             const float* __restrict__ query_pos,
                                             const float* __restrict__ qpe_w,
                                             const float* __restrict__ qpe_b,
                                             __bf16* __restrict__ qinb) {
  int i = blockIdx.x * 256 + threadIdx.x;
  int bq = i >> 8, c = i & 255;
  const float* qp = query_pos + (size_t)bq * 6;
  const float* w  = qpe_w + (size_t)c * 6;
  float acc = qpe_b[c];
#pragma unroll
  for (int j = 0; j < 6; ++j) acc += qp[j] * w[j];
  qinb[i] = (__bf16)(qtok[i] + acc);
}

// ---------------- box query: one wave per query token ----------------
__global__ __launch_bounds__(256) void k_boxq(const float* __restrict__ key_pos,
                                              const float* __restrict__ query_pos,
                                              int* __restrict__ idxo,
                                              int* __restrict__ masko) {
  __shared__ float kp[NK_ * 3];  // 48 KB
  int b = (blockIdx.x * 4) >> 10;
  const float* kpg = key_pos + (size_t)b * NK_ * 3;
  for (int t = threadIdx.x; t < NK_ * 3; t += 256) kp[t] = kpg[t];
  __syncthreads();
  int lane = threadIdx.x & 63;
  int q = blockIdx.x * 4 + (threadIdx.x >> 6);
  const float* qp = query_pos + (size_t)q * 6;
  float cx = qp[0], cy = qp[1], cz = qp[2];
  float hx = 0.5f * qp[3], hy = 0.5f * qp[4], hz = 0.5f * qp[5];
  int* iq = idxo + (size_t)q * S_;
  int found = 0;
  for (int ch = 0; ch < NK_ / 64; ++ch) {
    int k = ch * 64 + lane;
    float dx = fabsf(kp[k * 3 + 0] - cx);
    float dy = fabsf(kp[k * 3 + 1] - cy);
    float dz = fabsf(kp[k * 3 + 2] - cz);
    bool inside = (dx <= hx) && (dy <= hy) && (dz <= hz);
    unsigned long long bal = __ballot(inside);
    if (inside) {
      int slot = found + __popcll(bal & ((1ull << lane) - 1ull));
      if (slot < S_) iq[slot] = k;
    }
    found += __popcll(bal);
    if (found >= S_) break;
  }
  if (found > S_) found = S_;
  if (lane < S_) {
    int m = (lane < found) ? 0 : 1;
    if (lane >= found) iq[lane] = 0;
    if (lane == 0) m = 0;
    masko[(size_t)q * S_ + lane] = m;
  }
}

// ---------------- bf16 MFMA GEMM: out = A(M,K) @ Wn(N,K)^T + bias ----------
template <int RELU, int OUT_BF16>
__global__ __launch_bounds__(256) void k_gemm_bf16(
    const __bf16* __restrict__ A, const __bf16* __restrict__ Wn,
    const float* __restrict__ bias, void* __restrict__ outp,
    int M, int N, int K) {
  __shared__ __bf16 As[128][72];
  __shared__ __bf16 Bs[128][72];
  int n0 = blockIdx.x * 128, m0 = blockIdx.y * 128;
  int t = threadIdx.x;
  int lane = t & 63, w = t >> 6;
  int lane16 = lane & 15, quad = lane >> 4;
  int wm = (w & 1) * 64, wn = (w >> 1) * 64;

  f32x4 acc[4][4];
#pragma unroll
  for (int i = 0; i < 4; ++i)
#pragma unroll
    for (int j = 0; j < 4; ++j) acc[i][j] = (f32x4){0.f, 0.f, 0.f, 0.f};

  for (int k0 = 0; k0 < K; k0 += 64) {
#pragma unroll
    for (int i = 0; i < 4; ++i) {
      int ii = i * 256 + t;
      int m = ii >> 3, kc = (ii & 7) * 8;
      *(bf16x8*)&As[m][kc] = *(const bf16x8*)&A[(size_t)(m0 + m) * K + k0 + kc];
      *(bf16x8*)&Bs[m][kc] = *(const bf16x8*)&Wn[(size_t)(n0 + m) * K + k0 + kc];
    }
    __syncthreads();
#pragma unroll
    for (int kk = 0; kk < 64; kk += 32) {
      bf16x8 af[4], bfr[4];
#pragma unroll
      for (int i = 0; i < 4; ++i)
        af[i] = *(const bf16x8*)&As[wm + i * 16 + lane16][kk + quad * 8];
#pragma unroll
      for (int j = 0; j < 4; ++j)
        bfr[j] = *(const bf16x8*)&Bs[wn + j * 16 + lane16][kk + quad * 8];
#pragma unroll
      for (int i = 0; i < 4; ++i)
#pragma unroll
        for (int j = 0; j < 4; ++j)
          acc[i][j] = __builtin_amdgcn_mfma_f32_16x16x32_bf16(af[i], bfr[j], acc[i][j], 0, 0, 0);
    }
    __syncthreads();
  }

#pragma unroll
  for (int j = 0; j < 4; ++j) {
    int col = n0 + wn + j * 16 + lane16;
    float bv = bias[col];
#pragma unroll
    for (int i = 0; i < 4; ++i) {
#pragma unroll
      for (int r = 0; r < 4; ++r) {
        int row = m0 + wm + i * 16 + quad * 4 + r;
        float v = acc[i][j][r] + bv;
        if (RELU) v = fmaxf(v, 0.f);
        if (OUT_BF16)
          ((__bf16*)outp)[(size_t)row * N + col] = (__bf16)v;
        else
          ((float*)outp)[(size_t)row * N + col] = v;
      }
    }
  }
}

// ---- qkk[bq,h,c] = scale * sum_d qh[bq,h*32+d] * kwT[c][h*32+d] ------------
// K=32: single MFMA step, direct global operand loads. grid (C/128, BQ/128, H)
__global__ __launch_bounds__(256) void k_qkk(const __bf16* __restrict__ qhb,
                                             const __bf16* __restrict__ kwT,
                                             __bf16* __restrict__ qkkb) {
  int h = blockIdx.z;
  int n0 = blockIdx.x * 128, m0 = blockIdx.y * 128;
  int t = threadIdx.x;
  int lane = t & 63, w = t >> 6;
  int lane16 = lane & 15, quad = lane >> 4;
  int wm = (w & 1) * 64, wn = (w >> 1) * 64;
  f32x4 acc[4][4];
#pragma unroll
  for (int i = 0; i < 4; ++i)
#pragma unroll
    for (int j = 0; j < 4; ++j) acc[i][j] = (f32x4){0.f, 0.f, 0.f, 0.f};
  bf16x8 af[4], bfr[4];
#pragma unroll
  for (int i = 0; i < 4; ++i)
    af[i] = *(const bf16x8*)&qhb[(size_t)(m0 + wm + i * 16 + lane16) * C_ + h * 32 + quad * 8];
#pragma unroll
  for (int j = 0; j < 4; ++j)
    bfr[j] = *(const bf16x8*)&kwT[(size_t)(n0 + wn + j * 16 + lane16) * C_ + h * 32 + quad * 8];
#pragma unroll
  for (int i = 0; i < 4; ++i)
#pragma unroll
    for (int j = 0; j < 4; ++j)
      acc[i][j] = __builtin_amdgcn_mfma_f32_16x16x32_bf16(af[i], bfr[j], acc[i][j], 0, 0, 0);
#pragma unroll
  for (int j = 0; j < 4; ++j) {
    int col = n0 + wn + j * 16 + lane16;
#pragma unroll
    for (int i = 0; i < 4; ++i) {
#pragma unroll
      for (int r = 0; r < 4; ++r) {
        int row = m0 + wm + i * 16 + quad * 4 + r;
        qkkb[((size_t)row * H_ + h) * C_ + col] =
            (__bf16)(acc[i][j][r] * 0.17677669529663687f);
      }
    }
  }
}

// ---- qpk[bq*8+h] = scale * sum_d qh[bq,h*32+d] * Pk[h*32+d] ----------------
__global__ __launch_bounds__(256) void k_qpk(const __bf16* __restrict__ qhb,
                                             const float4* __restrict__ Pk,
                                             float4* __restrict__ qpk) {
  int i = blockIdx.x * 256 + threadIdx.x;  // bq*8+h
  int bq = i >> 3, h = i & 7;
  const __bf16* q = qhb + (size_t)bq * C_ + h * 32;
  float ax = 0.f, ay = 0.f, az = 0.f, aw = 0.f;
#pragma unroll
  for (int d = 0; d < 32; ++d) {
    float qv = (float)q[d];
    float4 p = Pk[h * 32 + d];
    ax += qv * p.x; ay += qv * p.y; az += qv * p.z; aw += qv * p.w;
  }
  const float sc = 0.17677669529663687f;
  qpk[i] = make_float4(ax * sc, ay * sc, az * sc, aw * sc);
}

// ---- fused attention: scores vs raw keys + softmax + y = P·X, pgx = P·gx ---
// one block per query token
__global__ __launch_bounds__(256) void k_attnfused(
    const __bf16* __restrict__ keyTb,     // (B, NK, C) bf16
    const float* __restrict__ key_pos,    // (B, NK, 3)
    const float* __restrict__ query_pos,  // (BQ, 6)
    const int* __restrict__ idx,          // (BQ, S)
    const int* __restrict__ maskb,        // (BQ, S)
    const __bf16* __restrict__ qkkb,      // (BQ, H, C)
    const float4* __restrict__ qpk,       // (BQ*H)
    __bf16* __restrict__ y,               // (H, BQ, C)
    float4* __restrict__ pgx) {           // (BQ*H)
  __shared__ __bf16 xs[S_][264];   // +8 pad: 528B row stride -> 2-way max
  __shared__ __bf16 qk[H_][264];
  __shared__ float sc[H_][S_];
  __shared__ float pw[H_][S_];
  __shared__ float4 gx4[S_];
  __shared__ int srow[S_], smask[S_];
  int bq = blockIdx.x, b = bq >> 10, t = threadIdx.x;

  if (t < S_) {
    int k = idx[(size_t)bq * S_ + t];
    srow[t] = b * NK_ + k;
    smask[t] = maskb[(size_t)bq * S_ + t];
    const float* kpp = key_pos + ((size_t)b * NK_ + k) * 3;
    const float* qp  = query_pos + (size_t)bq * 6;
    gx4[t] = make_float4(kpp[0] - qp[0], kpp[1] - qp[1], kpp[2] - qp[2], 1.f);
  }
  {  // stage qkk rows (H x 256)
    int h = t >> 5, c0 = (t & 31) * 8;
    *(bf16x8*)&qk[h][c0] = *(const bf16x8*)&qkkb[((size_t)bq * H_ + h) * C_ + c0];
  }
  __syncthreads();
  {  // stage gathered key rows (S x 256)
    int s = t >> 4, c0 = (t & 15) * 16;
    const __bf16* src = keyTb + (size_t)srow[s] * C_ + c0;
    *(bf16x8*)&xs[s][c0]     = *(const bf16x8*)&src[0];
    *(bf16x8*)&xs[s][c0 + 8] = *(const bf16x8*)&src[8];
  }
  __syncthreads();
  if (t < H_ * S_) {  // scores
    int h = t >> 4, s = t & (S_ - 1);
    float d = 0.f;
#pragma unroll
    for (int c0 = 0; c0 < C_; c0 += 8) {
      bf16x8 qv = *(const bf16x8*)&qk[h][c0];
      bf16x8 xv = *(const bf16x8*)&xs[s][c0];
#pragma unroll
      for (int j = 0; j < 8; ++j) d += (float)qv[j] * (float)xv[j];
    }
    float4 g = gx4[s];
    float4 pk = qpk[(size_t)bq * H_ + h];
    d += g.x * pk.x + g.y * pk.y + g.z * pk.z + pk.w;
    if (smask[s]) d = -1e30f;
    sc[h][s] = d;
  }
  __syncthreads();
  if (t < H_) {  // softmax + pgx
    float mx = -3.4e38f;
#pragma unroll
    for (int s = 0; s < S_; ++s) mx = fmaxf(mx, sc[t][s]);
    float e[S_], sum = 0.f;
#pragma unroll
    for (int s = 0; s < S_; ++s) { e[s] = expf(sc[t][s] - mx); sum += e[s]; }
    float inv = 1.f / sum;
    float gxx = 0.f, gyy = 0.f, gzz = 0.f;
#pragma unroll
    for (int s = 0; s < S_; ++s) {
      float p = e[s] * inv;
      pw[t][s] = p;
      float4 g = gx4[s];
      gxx += p * g.x; gyy += p * g.y; gzz += p * g.z;
    }
    pgx[(size_t)bq * H_ + t] = make_float4(gxx, gyy, gzz, 1.f);
  }
  __syncthreads();
#pragma unroll
  for (int h = 0; h < H_; ++h) {  // y[h][bq][c] = sum_s p * x
    float a = 0.f;
#pragma unroll
    for (int s = 0; s < S_; ++s) a += pw[h][s] * (float)xs[s][t];
    y[((size_t)h * BQ_ + bq) * C_ + t] = (__bf16)a;
  }
}

// ---- per-head v-projection: ao[bq, h*32+n] = vw[h*32+n,:]·y[h][bq,:] + pos --
// grid (BQ/128, H), 256 threads = 4 waves (2 M-halves x 2 N-halves)
__global__ __launch_bounds__(256) void k_vproj(
    const __bf16* __restrict__ y,      // (H, BQ, C)
    const __bf16* __restrict__ vwb,    // (C, C) bf16, rows = out channel
    const float4* __restrict__ Pv,     // (C)
    const float4* __restrict__ pgx,    // (BQ*H)
    __bf16* __restrict__ aob) {        // (BQ, C)
  __shared__ __bf16 As[128][72];
  __shared__ __bf16 Bs[32][72];
  int h = blockIdx.y;
  int m0 = blockIdx.x * 128;
  int t = threadIdx.x;
  int lane = t & 63, w = t >> 6;
  int lane16 = lane & 15, quad = lane >> 4;
  int wm = (w & 1) * 64, wn = (w >> 1) * 16;
  const __bf16* yh = y + (size_t)h * BQ_ * C_;

  f32x4 acc[4];
#pragma unroll
  for (int i = 0; i < 4; ++i) acc[i] = (f32x4){0.f, 0.f, 0.f, 0.f};

  for (int k0 = 0; k0 < C_; k0 += 64) {
#pragma unroll
    for (int i = 0; i < 4; ++i) {
      int ii = i * 256 + t;
      int m = ii >> 3, kc = (ii & 7) * 8;
      *(bf16x8*)&As[m][kc] = *(const bf16x8*)&yh[(size_t)(m0 + m) * C_ + k0 + kc];
    }
    {
      int m = t >> 3, kc = (t & 7) * 8;
      *(bf16x8*)&Bs[m][kc] = *(const bf16x8*)&vwb[(size_t)(h * 32 + m) * C_ + k0 + kc];
    }
    __syncthreads();
#pragma unroll
    for (int kk = 0; kk < 64; kk += 32) {
      bf16x8 bfr = *(const bf16x8*)&Bs[wn + lane16][kk + quad * 8];
#pragma unroll
      for (int i = 0; i < 4; ++i) {
        bf16x8 af = *(const bf16x8*)&As[wm + i * 16 + lane16][kk + quad * 8];
        acc[i] = __builtin_amdgcn_mfma_f32_16x16x32_bf16(af, bfr, acc[i], 0, 0, 0);
      }
    }
    __syncthreads();
  }
  int nloc = wn + lane16;
  int n = h * 32 + nloc;
  float4 pv = Pv[n];
#pragma unroll
  for (int i = 0; i < 4; ++i) {
#pragma unroll
    for (int r = 0; r < 4; ++r) {
      int row = m0 + wm + i * 16 + quad * 4 + r;
      float4 g = pgx[(size_t)row * H_ + h];
      float v = acc[i][r] + g.x * pv.x + g.y * pv.y + g.z * pv.z + pv.w;
      aob[(size_t)row * C_ + n] = (__bf16)v;
    }
  }
}

// ---------------- layernorm: out = LN(xa + xb)*g + b; optional bf16 copy ----
template <int WB>
__global__ __launch_bounds__(256) void k_ln(const float* __restrict__ xa,
                                            const float* __restrict__ xb,
                                            const float* __restrict__ g,
                                            const float* __restrict__ bb,
                                            float* __restrict__ outf,
                                            __bf16* __restrict__ outb) {
  int wid = (blockIdx.x * 256 + threadIdx.x) >> 6;
  int lane = threadIdx.x & 63;
  float4 va = *(const float4*)(xa + (size_t)wid * C_ + lane * 4);
  float4 vb = *(const float4*)(xb + (size_t)wid * C_ + lane * 4);
  float x0 = va.x + vb.x, x1 = va.y + vb.y, x2 = va.z + vb.z, x3 = va.w + vb.w;
  float s = x0 + x1 + x2 + x3;
#pragma unroll
  for (int off = 32; off >= 1; off >>= 1) s += __shfl_xor(s, off);
  float mean = s * (1.f / C_);
  float d0 = x0 - mean, d1 = x1 - mean, d2 = x2 - mean, d3 = x3 - mean;
  float v = d0 * d0 + d1 * d1 + d2 * d2 + d3 * d3;
#pragma unroll
  for (int off = 32; off >= 1; off >>= 1) v += __shfl_xor(v, off);
  float inv = 1.f / sqrtf(v * (1.f / C_) + EPS_);
  float4 g4 = *(const float4*)(g + lane * 4);
  float4 b4 = *(const float4*)(bb + lane * 4);
  float4 o;
  o.x = d0 * inv * g4.x + b4.x;
  o.y = d1 * inv * g4.y + b4.y;
  o.z = d2 * inv * g4.z + b4.z;
  o.w = d3 * inv * g4.w + b4.w;
  *(float4*)(outf + (size_t)wid * C_ + lane * 4) = o;
  if (WB) {
    __bf16* ob = outb + (size_t)wid * C_ + lane * 4;
    ob[0] = (__bf16)o.x; ob[1] = (__bf16)o.y; ob[2] = (__bf16)o.z; ob[3] = (__bf16)o.w;
  }
}

extern "C" void kernel_launch(void* const* d_in, const int* in_sizes, int n_in,
                              void* d_out, int out_size, void* d_ws, size_t ws_size,
                              hipStream_t stream) {
  const float* query     = (const float*)d_in[0];
  const float* key       = (const float*)d_in[1];
  const float* query_pos = (const float*)d_in[2];
  const float* key_pos   = (const float*)d_in[3];
  const float* q_w = (const float*)d_in[4];  const float* q_b = (const float*)d_in[5];
  const float* k_w = (const float*)d_in[6];  const float* k_b = (const float*)d_in[7];
  const float* v_w = (const float*)d_in[8];  const float* v_b = (const float*)d_in[9];
  const float* o_w = (const float*)d_in[10]; const float* o_b = (const float*)d_in[11];
  const float* lin1_w = (const float*)d_in[12]; const float* lin1_b = (const float*)d_in[13];
  const float* lin2_w = (const float*)d_in[14]; const float* lin2_b = (const float*)d_in[15];
  const float* n1_g = (const float*)d_in[16]; const float* n1_b = (const float*)d_in[17];
  const float* n2_g = (const float*)d_in[18]; const float* n2_b = (const float*)d_in[19];
  const float* qpe_w = (const float*)d_in[20]; const float* qpe_b = (const float*)d_in[21];
  const float* kpe_w = (const float*)d_in[22]; const float* kpe_b = (const float*)d_in[23];
  float* out = (float*)d_out;

  const size_t BQc = (size_t)BQ_ * C_;
  float* w = (float*)d_ws;
  size_t o = 0;
  // ---- workspace carve (~139 MB; R3's 142 MB passed) ----
  __bf16* keyTb = (__bf16*)(w + o); o += (size_t)B_ * NK_ * C_ / 2;  // 16.8 MB
  float* qtok  = w + o; o += BQc;
  float* x1    = w + o; o += BQc;
  float* attno = w + o; o += BQc;                                    // ff2o overlay
  float* x2    = w + o; o += BQc;
  __bf16* ybuf = (__bf16*)(w + o); o += BQc * H_ / 2;                // 33.5 MB (H,BQ,C)
  __bf16* qkkb = (__bf16*)(w + o); o += BQc * H_ / 2;                // 33.5 MB; ff1b overlay
  __bf16* qinb = (__bf16*)(w + o); o += BQc / 2;
  __bf16* qhb  = (__bf16*)(w + o); o += BQc / 2;
  __bf16* aob  = (__bf16*)(w + o); o += BQc / 2;
  __bf16* x1b  = (__bf16*)(w + o); o += BQc / 2;
  __bf16* qwb  = (__bf16*)(w + o); o += (size_t)C_ * C_ / 2;
  __bf16* kwT  = (__bf16*)(w + o); o += (size_t)C_ * C_ / 2;
  __bf16* vwb  = (__bf16*)(w + o); o += (size_t)C_ * C_ / 2;
  __bf16* owb  = (__bf16*)(w + o); o += (size_t)C_ * C_ / 2;
  __bf16* l1b  = (__bf16*)(w + o); o += (size_t)C_ * FF_ / 2;
  __bf16* l2b  = (__bf16*)(w + o); o += (size_t)C_ * FF_ / 2;
  float4* Pk   = (float4*)(w + o); o += C_ * 4;
  float4* Pv   = (float4*)(w + o); o += C_ * 4;
  float4* qpk  = (float4*)(w + o); o += (size_t)BQ_ * H_ * 4;        // 1 MB
  float4* pgx  = (float4*)(w + o); o += (size_t)BQ_ * H_ * 4;        // 1 MB
  int* idxb  = (int*)(w + o); o += (size_t)BQ_ * S_;
  int* maskb = (int*)(w + o); o += (size_t)BQ_ * S_;
  __bf16* ff1b = qkkb;      // qkk dead after attnfused
  float* ff2o  = attno;     // attno dead after LN1

  dim3 tb(32, 8);
  // layout transforms
  k_transb<<<dim3(NK_ / 32, C_ / 32, B_), tb, 0, stream>>>(key, keyTb, C_, NK_);
  k_transpose<<<dim3(NQ_ / 32, C_ / 32, B_), tb, 0, stream>>>(query, qtok, C_, NQ_);
  // weight casts / transposes
  k_cvt<<<C_ * C_ / 4 / 256, 256, 0, stream>>>(q_w, qwb, C_ * C_ / 4);
  k_transb<<<dim3(C_ / 32, C_ / 32, 1), tb, 0, stream>>>(k_w, kwT, C_, C_);  // kwT[c][d]=k_w[d][c]
  k_cvt<<<C_ * C_ / 4 / 256, 256, 0, stream>>>(v_w, vwb, C_ * C_ / 4);
  k_cvt<<<C_ * C_ / 4 / 256, 256, 0, stream>>>(o_w, owb, C_ * C_ / 4);
  k_cvt<<<C_ * FF_ / 4 / 256, 256, 0, stream>>>(lin1_w, l1b, C_ * FF_ / 4);
  k_cvt<<<C_ * FF_ / 4 / 256, 256, 0, stream>>>(lin2_w, l2b, C_ * FF_ / 4);
  // folded kpe projections
  k_pproj<<<1, 256, 0, stream>>>(k_w, k_b, kpe_w, kpe_b, Pk);
  k_pproj<<<1, 256, 0, stream>>>(v_w, v_b, kpe_w, kpe_b, Pv);
  // qin(bf16) = qtok + qpe
  k_qin<<<BQ_ * C_ / 256, 256, 0, stream>>>(qtok, query_pos, qpe_w, qpe_b, qinb);
  // box query
  k_boxq<<<BQ_ / 4, 256, 0, stream>>>(key_pos, query_pos, idxb, maskb);
  // qh = qin @ q_w.T + q_b
  k_gemm_bf16<0, 1><<<dim3(C_ / 128, BQ_ / 128), 256, 0, stream>>>(qinb, qwb, q_b, qhb, BQ_, C_, C_);
  // qkk = per-head qh @ k_w (scaled), qpk = folded kpe side
  k_qkk<<<dim3(C_ / 128, BQ_ / 128, H_), 256, 0, stream>>>(qhb, kwT, qkkb);
  k_qpk<<<BQ_ * H_ / 256, 256, 0, stream>>>(qhb, Pk, qpk);
  // fused attention: scores vs raw gathered keys, softmax, y & pgx
  k_attnfused<<<BQ_, 256, 0, stream>>>(keyTb, key_pos, query_pos, idxb, maskb,
                                       qkkb, qpk, ybuf, pgx);
  // ao = per-head v-projection of y + folded kpe
  k_vproj<<<dim3(BQ_ / 128, H_), 256, 0, stream>>>(ybuf, vwb, Pv, pgx, aob);
  // o projection (fp32 out)
  k_gemm_bf16<0, 0><<<dim3(C_ / 128, BQ_ / 128), 256, 0, stream>>>(aob, owb, o_b, attno, BQ_, C_, C_);
  // x1 = LN(qtok + attno), plus bf16 copy
  k_ln<1><<<BQ_ / 4, 256, 0, stream>>>(qtok, attno, n1_g, n1_b, x1, x1b);
  // ff1(bf16) = relu(x1 @ lin1.T + b)   [overlays qkkb]
  k_gemm_bf16<1, 1><<<dim3(FF_ / 128, BQ_ / 128), 256, 0, stream>>>(x1b, l1b, lin1_b, ff1b, BQ_, FF_, C_);
  // ff2(fp32) = ff1 @ lin2.T + b        [overlays attno]
  k_gemm_bf16<0, 0><<<dim3(C_ / 128, BQ_ / 128), 256, 0, stream>>>(ff1b, l2b, lin2_b, ff2o, BQ_, C_, FF_);
  // x2 = LN(x1 + ff2)
  k_ln<0><<<BQ_ / 4, 256, 0, stream>>>(x1, ff2o, n2_g, n2_b, x2, nullptr);
  // out (B, C, NQ) = transpose(x2 as (B, NQ, C))
  k_transpose<<<dim3(C_ / 32, NQ_ / 32, B_), tb, 0, stream>>>(x2, out, NQ_, C_);
}

// Round 5
// 337.986 us; speedup vs baseline: 3.1719x; 1.0691x over previous
//
#include <hip/hip_runtime.h>
#include <cstdint>

#define B_   8
#define C_   256
#define NQ_  1024
#define NK_  4096
#define S_   16
#define H_   8
#define FF_  2048
#define DH_  32
#define BQ_  (B_*NQ_)
#define EPS_ 1e-5f

typedef __bf16 bf16x8 __attribute__((ext_vector_type(8)));
typedef float  f32x4  __attribute__((ext_vector_type(4)));

// ---------------- fp32 transpose of last two dims ----------------
__global__ __launch_bounds__(256) void k_transpose(const float* __restrict__ in,
                                                   float* __restrict__ out,
                                                   int RI, int CJ) {
  __shared__ float t[32][33];
  int z = blockIdx.z;
  int j0 = blockIdx.x * 32, i0 = blockIdx.y * 32;
  const float* inz = in + (size_t)z * RI * CJ;
  float* outz = out + (size_t)z * RI * CJ;
  int tx = threadIdx.x, ty = threadIdx.y;
#pragma unroll
  for (int r = 0; r < 32; r += 8)
    t[ty + r][tx] = inz[(size_t)(i0 + ty + r) * CJ + (j0 + tx)];
  __syncthreads();
#pragma unroll
  for (int r = 0; r < 32; r += 8)
    outz[(size_t)(j0 + ty + r) * RI + (i0 + tx)] = t[tx][ty + r];
}

// ---------------- fp32 -> bf16 transpose ----------------
__global__ __launch_bounds__(256) void k_transb(const float* __restrict__ in,
                                                __bf16* __restrict__ out,
                                                int RI, int CJ) {
  __shared__ float t[32][33];
  int z = blockIdx.z;
  int j0 = blockIdx.x * 32, i0 = blockIdx.y * 32;
  const float* inz = in + (size_t)z * RI * CJ;
  __bf16* outz = out + (size_t)z * RI * CJ;
  int tx = threadIdx.x, ty = threadIdx.y;
#pragma unroll
  for (int r = 0; r < 32; r += 8)
    t[ty + r][tx] = inz[(size_t)(i0 + ty + r) * CJ + (j0 + tx)];
  __syncthreads();
#pragma unroll
  for (int r = 0; r < 32; r += 8)
    outz[(size_t)(j0 + ty + r) * RI + (i0 + tx)] = (__bf16)t[tx][ty + r];
}

// ---------------- fp32 -> bf16 convert ----------------
__global__ __launch_bounds__(256) void k_cvt(const float* __restrict__ in,
                                             __bf16* __restrict__ out, int n4) {
  int i = blockIdx.x * 256 + threadIdx.x;
  if (i >= n4) return;
  float4 v = *(const float4*)(in + (size_t)i * 4);
  __bf16* o = out + (size_t)i * 4;
  o[0] = (__bf16)v.x; o[1] = (__bf16)v.y; o[2] = (__bf16)v.z; o[3] = (__bf16)v.w;
}

// ---- P[n] = (kpe_w[:,0..2] dot w[n,:], kpe_b dot w[n,:] + wb[n]) -----------
__global__ __launch_bounds__(256) void k_pproj(const float* __restrict__ w,
                                               const float* __restrict__ wb,
                                               const float* __restrict__ kpw,
                                               const float* __restrict__ kpb,
                                               float4* __restrict__ P) {
  int n = threadIdx.x;
  const float* wr = w + (size_t)n * C_;
  float p0 = 0.f, p1 = 0.f, p2 = 0.f, pb = 0.f;
  for (int k = 0; k < C_; ++k) {
    float wv = wr[k];
    p0 += kpw[k * 3 + 0] * wv;
    p1 += kpw[k * 3 + 1] * wv;
    p2 += kpw[k * 3 + 2] * wv;
    pb += kpb[k] * wv;
  }
  P[n] = make_float4(p0, p1, p2, pb + wb[n]);
}

// ---------------- qin(bf16) = qtok + query_pos @ qpe_w.T + qpe_b ----------
__global__ __launch_bounds__(256) void k_qin(const float* __restrict__ qtok,
                                             const float* __restrict__ query_pos,
                                             const float* __restrict__ qpe_w,
                                             const float* __restrict__ qpe_b,
                                             __bf16* __restrict__ qinb) {
  int i = blockIdx.x * 256 + threadIdx.x;
  int bq = i >> 8, c = i & 255;
  const float* qp = query_pos + (size_t)bq * 6;
  const float* w  = qpe_w + (size_t)c * 6;
  float acc = qpe_b[c];
#pragma unroll
  for (int j = 0; j < 6; ++j) acc += qp[j] * w[j];
  qinb[i] = (__bf16)(qtok[i] + acc);
}

// ---------------- box query: one wave per query token ----------------
__global__ __launch_bounds__(256) void k_boxq(const float* __restrict__ key_pos,
                                              const float* __restrict__ query_pos,
                                              int* __restrict__ idxo,
                                              int* __restrict__ masko) {
  __shared__ float kp[NK_ * 3];  // 48 KB
  int b = (blockIdx.x * 4) >> 10;
  const float* kpg = key_pos + (size_t)b * NK_ * 3;
  for (int t = threadIdx.x; t < NK_ * 3; t += 256) kp[t] = kpg[t];
  __syncthreads();
  int lane = threadIdx.x & 63;
  int q = blockIdx.x * 4 + (threadIdx.x >> 6);
  const float* qp = query_pos + (size_t)q * 6;
  float cx = qp[0], cy = qp[1], cz = qp[2];
  float hx = 0.5f * qp[3], hy = 0.5f * qp[4], hz = 0.5f * qp[5];
  int* iq = idxo + (size_t)q * S_;
  int found = 0;
  for (int ch = 0; ch < NK_ / 64; ++ch) {
    int k = ch * 64 + lane;
    float dx = fabsf(kp[k * 3 + 0] - cx);
    float dy = fabsf(kp[k * 3 + 1] - cy);
    float dz = fabsf(kp[k * 3 + 2] - cz);
    bool inside = (dx <= hx) && (dy <= hy) && (dz <= hz);
    unsigned long long bal = __ballot(inside);
    if (inside) {
      int slot = found + __popcll(bal & ((1ull << lane) - 1ull));
      if (slot < S_) iq[slot] = k;
    }
    found += __popcll(bal);
    if (found >= S_) break;
  }
  if (found > S_) found = S_;
  if (lane < S_) {
    int m = (lane < found) ? 0 : 1;
    if (lane >= found) iq[lane] = 0;
    if (lane == 0) m = 0;
    masko[(size_t)q * S_ + lane] = m;
  }
}

// ---------------- bf16 MFMA GEMM: out = A(M,K) @ Wn(N,K)^T + bias ----------
// BM=128, BN template (128 or 64), BK=64, 256 threads = 4 waves 2x2
template <int BN, int RELU, int OUT_BF16>
__global__ __launch_bounds__(256) void k_gemm_bf16(
    const __bf16* __restrict__ A, const __bf16* __restrict__ Wn,
    const float* __restrict__ bias, void* __restrict__ outp,
    int M, int N, int K) {
  constexpr int JN = BN / 32;  // B frags per wave
  __shared__ __bf16 As[128][72];
  __shared__ __bf16 Bs[BN][72];
  int n0 = blockIdx.x * BN, m0 = blockIdx.y * 128;
  int t = threadIdx.x;
  int lane = t & 63, w = t >> 6;
  int lane16 = lane & 15, quad = lane >> 4;
  int wm = (w & 1) * 64, wn = (w >> 1) * (BN / 2);

  f32x4 acc[4][JN];
#pragma unroll
  for (int i = 0; i < 4; ++i)
#pragma unroll
    for (int j = 0; j < JN; ++j) acc[i][j] = (f32x4){0.f, 0.f, 0.f, 0.f};

  for (int k0 = 0; k0 < K; k0 += 64) {
#pragma unroll
    for (int i = 0; i < 4; ++i) {
      int ii = i * 256 + t;
      int m = ii >> 3, kc = (ii & 7) * 8;
      *(bf16x8*)&As[m][kc] = *(const bf16x8*)&A[(size_t)(m0 + m) * K + k0 + kc];
    }
#pragma unroll
    for (int i = 0; i < JN; ++i) {
      int ii = i * 256 + t;
      int m = ii >> 3, kc = (ii & 7) * 8;
      *(bf16x8*)&Bs[m][kc] = *(const bf16x8*)&Wn[(size_t)(n0 + m) * K + k0 + kc];
    }
    __syncthreads();
#pragma unroll
    for (int kk = 0; kk < 64; kk += 32) {
      bf16x8 af[4], bfr[JN];
#pragma unroll
      for (int i = 0; i < 4; ++i)
        af[i] = *(const bf16x8*)&As[wm + i * 16 + lane16][kk + quad * 8];
#pragma unroll
      for (int j = 0; j < JN; ++j)
        bfr[j] = *(const bf16x8*)&Bs[wn + j * 16 + lane16][kk + quad * 8];
#pragma unroll
      for (int i = 0; i < 4; ++i)
#pragma unroll
        for (int j = 0; j < JN; ++j)
          acc[i][j] = __builtin_amdgcn_mfma_f32_16x16x32_bf16(af[i], bfr[j], acc[i][j], 0, 0, 0);
    }
    __syncthreads();
  }

#pragma unroll
  for (int j = 0; j < JN; ++j) {
    int col = n0 + wn + j * 16 + lane16;
    float bv = bias ? bias[col] : 0.f;
#pragma unroll
    for (int i = 0; i < 4; ++i) {
#pragma unroll
      for (int r = 0; r < 4; ++r) {
        int row = m0 + wm + i * 16 + quad * 4 + r;
        float v = acc[i][j][r] + bv;
        if (RELU) v = fmaxf(v, 0.f);
        if (OUT_BF16)
          ((__bf16*)outp)[(size_t)row * N + col] = (__bf16)v;
        else
          ((float*)outp)[(size_t)row * N + col] = v;
      }
    }
  }
}

// ---- qpk[bq*8+h] = scale * sum_d qh[bq,h*32+d] * Pk[h*32+d] ----------------
__global__ __launch_bounds__(256) void k_qpk(const __bf16* __restrict__ qhb,
                                             const float4* __restrict__ Pk,
                                             float4* __restrict__ qpk) {
  int i = blockIdx.x * 256 + threadIdx.x;  // bq*8+h
  int bq = i >> 3, h = i & 7;
  const __bf16* q = qhb + (size_t)bq * C_ + h * 32;
  float ax = 0.f, ay = 0.f, az = 0.f, aw = 0.f;
#pragma unroll
  for (int d = 0; d < 32; ++d) {
    float qv = (float)q[d];
    float4 p = Pk[h * 32 + d];
    ax += qv * p.x; ay += qv * p.y; az += qv * p.z; aw += qv * p.w;
  }
  const float sc = 0.17677669529663687f;
  qpk[i] = make_float4(ax * sc, ay * sc, az * sc, aw * sc);
}

// ---- fused attention v3: gather per-key kh|vh, scores (32-MAC/head),
//      softmax, PV (16-MAC/thread), kpe folds via qpk/Pk & pgx/Pv in-LDS.
// one block per query token.
__global__ __launch_bounds__(256) void k_attnf(
    const __bf16* __restrict__ khv,       // (B*NK, 512): [kh|vh] per key
    const float* __restrict__ key_pos,    // (B, NK, 3)
    const float* __restrict__ query_pos,  // (BQ, 6)
    const int* __restrict__ idx,          // (BQ, S)
    const int* __restrict__ maskb,        // (BQ, S)
    const __bf16* __restrict__ qhb,       // (BQ, C)
    const float4* __restrict__ qpk,       // (BQ*H), scale folded
    const float4* __restrict__ Pv,        // (C)
    __bf16* __restrict__ aob) {           // (BQ, C)
  __shared__ __bf16 kvs[S_][520];  // 512 + 8 pad
  __shared__ float qrow[C_];
  __shared__ float sc[H_][S_];
  __shared__ float pw[H_][S_];
  __shared__ float4 gx4[S_];
  __shared__ float4 pgxs[H_];
  __shared__ int srow[S_], smask[S_];
  int bq = blockIdx.x, b = bq >> 10, t = threadIdx.x;

  if (t < S_) {
    int k = idx[(size_t)bq * S_ + t];
    srow[t] = b * NK_ + k;
    smask[t] = maskb[(size_t)bq * S_ + t];
    const float* kpp = key_pos + ((size_t)b * NK_ + k) * 3;
    const float* qp  = query_pos + (size_t)bq * 6;
    gx4[t] = make_float4(kpp[0] - qp[0], kpp[1] - qp[1], kpp[2] - qp[2], 1.f);
  }
  qrow[t] = (float)qhb[(size_t)bq * C_ + t];
  __syncthreads();
  {  // gather khv rows: 16 rows x 1KB contiguous
    int s = t >> 4, c0 = (t & 15) * 32;
    const __bf16* src = khv + (size_t)srow[s] * 512 + c0;
    *(bf16x8*)&kvs[s][c0]      = *(const bf16x8*)&src[0];
    *(bf16x8*)&kvs[s][c0 + 8]  = *(const bf16x8*)&src[8];
    *(bf16x8*)&kvs[s][c0 + 16] = *(const bf16x8*)&src[16];
    *(bf16x8*)&kvs[s][c0 + 24] = *(const bf16x8*)&src[24];
  }
  __syncthreads();
  if (t < H_ * S_) {  // scores: 32-MAC per-head dot
    int h = t >> 4, s = t & (S_ - 1);
    float d = 0.f;
#pragma unroll
    for (int c0 = 0; c0 < 32; c0 += 8) {
      bf16x8 xv = *(const bf16x8*)&kvs[s][h * 32 + c0];
#pragma unroll
      for (int j = 0; j < 8; ++j) d += qrow[h * 32 + c0 + j] * (float)xv[j];
    }
    d *= 0.17677669529663687f;
    float4 g = gx4[s];
    float4 pk = qpk[(size_t)bq * H_ + h];
    d += g.x * pk.x + g.y * pk.y + g.z * pk.z + pk.w;
    if (smask[s]) d = -1e30f;
    sc[h][s] = d;
  }
  __syncthreads();
  if (t < H_) {  // softmax + pgx (stays in LDS)
    float mx = -3.4e38f;
#pragma unroll
    for (int s = 0; s < S_; ++s) mx = fmaxf(mx, sc[t][s]);
    float e[S_], sum = 0.f;
#pragma unroll
    for (int s = 0; s < S_; ++s) { e[s] = expf(sc[t][s] - mx); sum += e[s]; }
    float inv = 1.f / sum;
    float gxx = 0.f, gyy = 0.f, gzz = 0.f;
#pragma unroll
    for (int s = 0; s < S_; ++s) {
      float p = e[s] * inv;
      pw[t][s] = p;
      float4 g = gx4[s];
      gxx += p * g.x; gyy += p * g.y; gzz += p * g.z;
    }
    pgxs[t] = make_float4(gxx, gyy, gzz, 1.f);
  }
  __syncthreads();
  {  // PV: thread t = output channel; only its own head's 16 slots
    int h = t >> 5;
    float a = 0.f;
#pragma unroll
    for (int s = 0; s < S_; ++s) a += pw[h][s] * (float)kvs[s][256 + t];
    float4 pv = Pv[t];
    float4 g = pgxs[h];
    a += g.x * pv.x + g.y * pv.y + g.z * pv.z + pv.w;
    aob[(size_t)bq * C_ + t] = (__bf16)a;
  }
}

// ---------------- layernorm: out = LN(xa + xb)*g + b; optional bf16 copy ----
template <int WB>
__global__ __launch_bounds__(256) void k_ln(const float* __restrict__ xa,
                                            const float* __restrict__ xb,
                                            const float* __restrict__ g,
                                            const float* __restrict__ bb,
                                            float* __restrict__ outf,
                                            __bf16* __restrict__ outb) {
  int wid = (blockIdx.x * 256 + threadIdx.x) >> 6;
  int lane = threadIdx.x & 63;
  float4 va = *(const float4*)(xa + (size_t)wid * C_ + lane * 4);
  float4 vb = *(const float4*)(xb + (size_t)wid * C_ + lane * 4);
  float x0 = va.x + vb.x, x1 = va.y + vb.y, x2 = va.z + vb.z, x3 = va.w + vb.w;
  float s = x0 + x1 + x2 + x3;
#pragma unroll
  for (int off = 32; off >= 1; off >>= 1) s += __shfl_xor(s, off);
  float mean = s * (1.f / C_);
  float d0 = x0 - mean, d1 = x1 - mean, d2 = x2 - mean, d3 = x3 - mean;
  float v = d0 * d0 + d1 * d1 + d2 * d2 + d3 * d3;
#pragma unroll
  for (int off = 32; off >= 1; off >>= 1) v += __shfl_xor(v, off);
  float inv = 1.f / sqrtf(v * (1.f / C_) + EPS_);
  float4 g4 = *(const float4*)(g + lane * 4);
  float4 b4 = *(const float4*)(bb + lane * 4);
  float4 o;
  o.x = d0 * inv * g4.x + b4.x;
  o.y = d1 * inv * g4.y + b4.y;
  o.z = d2 * inv * g4.z + b4.z;
  o.w = d3 * inv * g4.w + b4.w;
  *(float4*)(outf + (size_t)wid * C_ + lane * 4) = o;
  if (WB) {
    __bf16* ob = outb + (size_t)wid * C_ + lane * 4;
    ob[0] = (__bf16)o.x; ob[1] = (__bf16)o.y; ob[2] = (__bf16)o.z; ob[3] = (__bf16)o.w;
  }
}

extern "C" void kernel_launch(void* const* d_in, const int* in_sizes, int n_in,
                              void* d_out, int out_size, void* d_ws, size_t ws_size,
                              hipStream_t stream) {
  const float* query     = (const float*)d_in[0];
  const float* key       = (const float*)d_in[1];
  const float* query_pos = (const float*)d_in[2];
  const float* key_pos   = (const float*)d_in[3];
  const float* q_w = (const float*)d_in[4];  const float* q_b = (const float*)d_in[5];
  const float* k_w = (const float*)d_in[6];  const float* k_b = (const float*)d_in[7];
  const float* v_w = (const float*)d_in[8];  const float* v_b = (const float*)d_in[9];
  const float* o_w = (const float*)d_in[10]; const float* o_b = (const float*)d_in[11];
  const float* lin1_w = (const float*)d_in[12]; const float* lin1_b = (const float*)d_in[13];
  const float* lin2_w = (const float*)d_in[14]; const float* lin2_b = (const float*)d_in[15];
  const float* n1_g = (const float*)d_in[16]; const float* n1_b = (const float*)d_in[17];
  const float* n2_g = (const float*)d_in[18]; const float* n2_b = (const float*)d_in[19];
  const float* qpe_w = (const float*)d_in[20]; const float* qpe_b = (const float*)d_in[21];
  const float* kpe_w = (const float*)d_in[22]; const float* kpe_b = (const float*)d_in[23];
  float* out = (float*)d_out;

  const size_t BQc = (size_t)BQ_ * C_;
  float* w = (float*)d_ws;
  size_t o = 0;
  // ---- workspace carve (~106 MB) ----
  __bf16* keyTb = (__bf16*)(w + o); o += (size_t)B_ * NK_ * C_ / 2;   // 16.8 MB
  float* qtok  = w + o; o += BQc;
  float* x1    = w + o; o += BQc;
  float* attno = w + o; o += BQc;                                     // ff2o overlay
  float* x2    = w + o; o += BQc;
  __bf16* khvbuf = (__bf16*)(w + o); o += (size_t)B_ * NK_ * 512 / 2; // 33.5 MB; ff1b overlay
  __bf16* qinb = (__bf16*)(w + o); o += BQc / 2;
  __bf16* qhb  = (__bf16*)(w + o); o += BQc / 2;
  __bf16* aob  = (__bf16*)(w + o); o += BQc / 2;
  __bf16* x1b  = (__bf16*)(w + o); o += BQc / 2;
  __bf16* qwb  = (__bf16*)(w + o); o += (size_t)C_ * C_ / 2;
  __bf16* kvwb = (__bf16*)(w + o); o += (size_t)C_ * C_;              // (512,256) = k_w ++ v_w
  __bf16* owb  = (__bf16*)(w + o); o += (size_t)C_ * C_ / 2;
  __bf16* l1b  = (__bf16*)(w + o); o += (size_t)C_ * FF_ / 2;
  __bf16* l2b  = (__bf16*)(w + o); o += (size_t)C_ * FF_ / 2;
  float4* Pk   = (float4*)(w + o); o += C_ * 4;
  float4* Pv   = (float4*)(w + o); o += C_ * 4;
  float4* qpk  = (float4*)(w + o); o += (size_t)BQ_ * H_ * 4;         // 1 MB
  int* idxb  = (int*)(w + o); o += (size_t)BQ_ * S_;
  int* maskb = (int*)(w + o); o += (size_t)BQ_ * S_;
  __bf16* ff1b = khvbuf;    // khv dead after attnf
  float* ff2o  = attno;     // attno dead after LN1

  dim3 tb(32, 8);
  // layout transforms
  k_transb<<<dim3(NK_ / 32, C_ / 32, B_), tb, 0, stream>>>(key, keyTb, C_, NK_);
  k_transpose<<<dim3(NQ_ / 32, C_ / 32, B_), tb, 0, stream>>>(query, qtok, C_, NQ_);
  // weight casts ((N,K) row-major = MFMA B-operand layout)
  k_cvt<<<C_ * C_ / 4 / 256, 256, 0, stream>>>(q_w, qwb, C_ * C_ / 4);
  k_cvt<<<C_ * C_ / 4 / 256, 256, 0, stream>>>(k_w, kvwb, C_ * C_ / 4);
  k_cvt<<<C_ * C_ / 4 / 256, 256, 0, stream>>>(v_w, kvwb + (size_t)C_ * C_, C_ * C_ / 4);
  k_cvt<<<C_ * C_ / 4 / 256, 256, 0, stream>>>(o_w, owb, C_ * C_ / 4);
  k_cvt<<<C_ * FF_ / 4 / 256, 256, 0, stream>>>(lin1_w, l1b, C_ * FF_ / 4);
  k_cvt<<<C_ * FF_ / 4 / 256, 256, 0, stream>>>(lin2_w, l2b, C_ * FF_ / 4);
  // folded kpe projections
  k_pproj<<<1, 256, 0, stream>>>(k_w, k_b, kpe_w, kpe_b, Pk);
  k_pproj<<<1, 256, 0, stream>>>(v_w, v_b, kpe_w, kpe_b, Pv);
  // qin(bf16) = qtok + qpe
  k_qin<<<BQ_ * C_ / 256, 256, 0, stream>>>(qtok, query_pos, qpe_w, qpe_b, qinb);
  // box query
  k_boxq<<<BQ_ / 4, 256, 0, stream>>>(key_pos, query_pos, idxb, maskb);
  // khv[b,k,:] = key_feat @ [k_w|v_w]^T  (per UNIQUE key; no bias — folded)
  k_gemm_bf16<128, 0, 1><<<dim3(512 / 128, B_ * NK_ / 128), 256, 0, stream>>>(
      keyTb, kvwb, nullptr, khvbuf, B_ * NK_, 512, C_);
  // qh = qin @ q_w.T + q_b
  k_gemm_bf16<64, 0, 1><<<dim3(C_ / 64, BQ_ / 128), 256, 0, stream>>>(qinb, qwb, q_b, qhb, BQ_, C_, C_);
  // qpk = folded kpe side of scores
  k_qpk<<<BQ_ * H_ / 256, 256, 0, stream>>>(qhb, Pk, qpk);
  // fused attention
  k_attnf<<<BQ_, 256, 0, stream>>>(khvbuf, key_pos, query_pos, idxb, maskb,
                                   qhb, qpk, Pv, aob);
  // o projection (fp32 out)
  k_gemm_bf16<64, 0, 0><<<dim3(C_ / 64, BQ_ / 128), 256, 0, stream>>>(aob, owb, o_b, attno, BQ_, C_, C_);
  // x1 = LN(qtok + attno), plus bf16 copy
  k_ln<1><<<BQ_ / 4, 256, 0, stream>>>(qtok, attno, n1_g, n1_b, x1, x1b);
  // ff1(bf16) = relu(x1 @ lin1.T + b)   [overlays khvbuf]
  k_gemm_bf16<128, 1, 1><<<dim3(FF_ / 128, BQ_ / 128), 256, 0, stream>>>(x1b, l1b, lin1_b, ff1b, BQ_, FF_, C_);
  // ff2(fp32) = ff1 @ lin2.T + b        [overlays attno]
  k_gemm_bf16<64, 0, 0><<<dim3(C_ / 64, BQ_ / 128), 256, 0, stream>>>(ff1b, l2b, lin2_b, ff2o, BQ_, C_, FF_);
  // x2 = LN(x1 + ff2)
  k_ln<0><<<BQ_ / 4, 256, 0, stream>>>(x1, ff2o, n2_g, n2_b, x2, nullptr);
  // out (B, C, NQ) = transpose(x2 as (B, NQ, C))
  k_transpose<<<dim3(C_ / 32, NQ_ / 32, B_), tb, 0, stream>>>(x2, out, NQ_, C_);
}

// Round 6
// 297.176 us; speedup vs baseline: 3.6075x; 1.1373x over previous
//
#include <hip/hip_runtime.h>
#include <cstdint>

#define B_   8
#define C_   256
#define NQ_  1024
#define NK_  4096
#define S_   16
#define H_   8
#define FF_  2048
#define DH_  32
#define BQ_  (B_*NQ_)
#define EPS_ 1e-5f

typedef __bf16 bf16x8 __attribute__((ext_vector_type(8)));
typedef float  f32x4  __attribute__((ext_vector_type(4)));

// ---------------- fp32 -> bf16 transpose (for key -> keyTb) ----------------
__global__ __launch_bounds__(256) void k_transb(const float* __restrict__ in,
                                                __bf16* __restrict__ out,
                                                int RI, int CJ) {
  __shared__ float t[32][33];
  int z = blockIdx.z;
  int j0 = blockIdx.x * 32, i0 = blockIdx.y * 32;
  const float* inz = in + (size_t)z * RI * CJ;
  __bf16* outz = out + (size_t)z * RI * CJ;
  int tx = threadIdx.x, ty = threadIdx.y;
#pragma unroll
  for (int r = 0; r < 32; r += 8)
    t[ty + r][tx] = inz[(size_t)(i0 + ty + r) * CJ + (j0 + tx)];
  __syncthreads();
#pragma unroll
  for (int r = 0; r < 32; r += 8)
    outz[(size_t)(j0 + ty + r) * RI + (i0 + tx)] = (__bf16)t[tx][ty + r];
}

// ---- fused query transpose + qpe: qtok(fp32, BQ x C) and qinb(bf16) -------
// query (B, C, NQ) -> row-major (BQ, C); qinb = qtok + query_pos@qpe_w.T+qpe_b
// grid (NQ/32, C/32, B), block (32,8)
__global__ __launch_bounds__(256) void k_transq(const float* __restrict__ query,
                                                const float* __restrict__ query_pos,
                                                const float* __restrict__ qpe_w,
                                                const float* __restrict__ qpe_b,
                                                float* __restrict__ qtok,
                                                __bf16* __restrict__ qinb) {
  __shared__ float t[32][33];
  __shared__ float sqp[32][6];
  int z = blockIdx.z;
  int nq0 = blockIdx.x * 32, c0 = blockIdx.y * 32;
  const float* inz = query + (size_t)z * C_ * NQ_;
  int tx = threadIdx.x, ty = threadIdx.y;
  int t1d = ty * 32 + tx;
#pragma unroll
  for (int r = 0; r < 32; r += 8)
    t[ty + r][tx] = inz[(size_t)(c0 + ty + r) * NQ_ + (nq0 + tx)];
  if (t1d < 192)
    sqp[t1d / 6][t1d % 6] = query_pos[((size_t)z * NQ_ + nq0 + t1d / 6) * 6 + (t1d % 6)];
  int c = c0 + tx;
  float w0 = qpe_w[c * 6 + 0], w1 = qpe_w[c * 6 + 1], w2 = qpe_w[c * 6 + 2];
  float w3 = qpe_w[c * 6 + 3], w4 = qpe_w[c * 6 + 4], w5 = qpe_w[c * 6 + 5];
  float wb = qpe_b[c];
  __syncthreads();
#pragma unroll
  for (int r = 0; r < 32; r += 8) {
    int nql = ty + r;
    size_t row = (size_t)z * NQ_ + nq0 + nql;
    float v = t[tx][nql];
    float pe = wb + sqp[nql][0] * w0 + sqp[nql][1] * w1 + sqp[nql][2] * w2 +
               sqp[nql][3] * w3 + sqp[nql][4] * w4 + sqp[nql][5] * w5;
    qtok[row * C_ + c] = v;
    qinb[row * C_ + c] = (__bf16)(v + pe);
  }
}

// ---------------- all weight casts in one launch ----------------
struct CvtArgs {
  const float* src[6];
  __bf16* dst[6];
};
// block sizes (in 1024-elem blocks): 64,64,64,64,512,512 -> cum 64,128,192,256,768,1280
__global__ __launch_bounds__(256) void k_cvt_all(CvtArgs a) {
  int blk = blockIdx.x;
  int idx, base;
  if (blk < 64)       { idx = 0; base = blk; }
  else if (blk < 128) { idx = 1; base = blk - 64; }
  else if (blk < 192) { idx = 2; base = blk - 128; }
  else if (blk < 256) { idx = 3; base = blk - 192; }
  else if (blk < 768) { idx = 4; base = blk - 256; }
  else                { idx = 5; base = blk - 768; }
  size_t off = (size_t)base * 1024 + threadIdx.x * 4;
  float4 v = *(const float4*)(a.src[idx] + off);
  __bf16* o = a.dst[idx] + off;
  o[0] = (__bf16)v.x; o[1] = (__bf16)v.y; o[2] = (__bf16)v.z; o[3] = (__bf16)v.w;
}

// ---- P[n] = (kpe_w[:,j] dot w[n,:], kpe_b dot w[n,:] + wb[n]) --------------
// grid (8, 2): y selects k/v; x covers 32 n each. 256 thr = 32 n x 8 k-slices
__global__ __launch_bounds__(256) void k_pproj2(const float* __restrict__ kw,
                                                const float* __restrict__ kb,
                                                const float* __restrict__ vw,
                                                const float* __restrict__ vb,
                                                const float* __restrict__ kpw,
                                                const float* __restrict__ kpb,
                                                float4* __restrict__ Pk,
                                                float4* __restrict__ Pv) {
  const float* w  = blockIdx.y ? vw : kw;
  const float* wb = blockIdx.y ? vb : kb;
  float4* P = blockIdx.y ? Pv : Pk;
  __shared__ float4 red[32][8];
  int t = threadIdx.x;
  int nl = t >> 3, ks = (t & 7) * 32;
  int n = blockIdx.x * 32 + nl;
  const float* wr = w + (size_t)n * C_;
  float p0 = 0.f, p1 = 0.f, p2 = 0.f, pb = 0.f;
#pragma unroll
  for (int k = ks; k < ks + 32; ++k) {
    float wv = wr[k];
    p0 += kpw[k * 3 + 0] * wv;
    p1 += kpw[k * 3 + 1] * wv;
    p2 += kpw[k * 3 + 2] * wv;
    pb += kpb[k] * wv;
  }
  red[nl][t & 7] = make_float4(p0, p1, p2, pb);
  __syncthreads();
  if (t < 32) {
    float4 s = red[t][0];
#pragma unroll
    for (int j = 1; j < 8; ++j) {
      float4 r = red[t][j];
      s.x += r.x; s.y += r.y; s.z += r.z; s.w += r.w;
    }
    s.w += wb[blockIdx.x * 32 + t];
    P[blockIdx.x * 32 + t] = s;
  }
}

// ---------------- box query: one wave per query token ----------------
__global__ __launch_bounds__(256) void k_boxq(const float* __restrict__ key_pos,
                                              const float* __restrict__ query_pos,
                                              int* __restrict__ idxo,
                                              int* __restrict__ masko) {
  __shared__ float kp[NK_ * 3];  // 48 KB
  int b = (blockIdx.x * 4) >> 10;
  const float* kpg = key_pos + (size_t)b * NK_ * 3;
  for (int t = threadIdx.x; t < NK_ * 3; t += 256) kp[t] = kpg[t];
  __syncthreads();
  int lane = threadIdx.x & 63;
  int q = blockIdx.x * 4 + (threadIdx.x >> 6);
  const float* qp = query_pos + (size_t)q * 6;
  float cx = qp[0], cy = qp[1], cz = qp[2];
  float hx = 0.5f * qp[3], hy = 0.5f * qp[4], hz = 0.5f * qp[5];
  int* iq = idxo + (size_t)q * S_;
  int found = 0;
  for (int ch = 0; ch < NK_ / 64; ++ch) {
    int k = ch * 64 + lane;
    float dx = fabsf(kp[k * 3 + 0] - cx);
    float dy = fabsf(kp[k * 3 + 1] - cy);
    float dz = fabsf(kp[k * 3 + 2] - cz);
    bool inside = (dx <= hx) && (dy <= hy) && (dz <= hz);
    unsigned long long bal = __ballot(inside);
    if (inside) {
      int slot = found + __popcll(bal & ((1ull << lane) - 1ull));
      if (slot < S_) iq[slot] = k;
    }
    found += __popcll(bal);
    if (found >= S_) break;
  }
  if (found > S_) found = S_;
  if (lane < S_) {
    int m = (lane < found) ? 0 : 1;
    if (lane >= found) iq[lane] = 0;
    if (lane == 0) m = 0;
    masko[(size_t)q * S_ + lane] = m;
  }
}

// ---------------- bf16 MFMA GEMM: out = A(M,K) @ Wn(N,K)^T + bias ----------
template <int BN, int RELU, int OUT_BF16>
__global__ __launch_bounds__(256) void k_gemm_bf16(
    const __bf16* __restrict__ A, const __bf16* __restrict__ Wn,
    const float* __restrict__ bias, void* __restrict__ outp,
    int M, int N, int K) {
  constexpr int JN = BN / 32;
  __shared__ __bf16 As[128][72];
  __shared__ __bf16 Bs[BN][72];
  int n0 = blockIdx.x * BN, m0 = blockIdx.y * 128;
  int t = threadIdx.x;
  int lane = t & 63, w = t >> 6;
  int lane16 = lane & 15, quad = lane >> 4;
  int wm = (w & 1) * 64, wn = (w >> 1) * (BN / 2);

  f32x4 acc[4][JN];
#pragma unroll
  for (int i = 0; i < 4; ++i)
#pragma unroll
    for (int j = 0; j < JN; ++j) acc[i][j] = (f32x4){0.f, 0.f, 0.f, 0.f};

  for (int k0 = 0; k0 < K; k0 += 64) {
#pragma unroll
    for (int i = 0; i < 4; ++i) {
      int ii = i * 256 + t;
      int m = ii >> 3, kc = (ii & 7) * 8;
      *(bf16x8*)&As[m][kc] = *(const bf16x8*)&A[(size_t)(m0 + m) * K + k0 + kc];
    }
#pragma unroll
    for (int i = 0; i < JN; ++i) {
      int ii = i * 256 + t;
      int m = ii >> 3, kc = (ii & 7) * 8;
      *(bf16x8*)&Bs[m][kc] = *(const bf16x8*)&Wn[(size_t)(n0 + m) * K + k0 + kc];
    }
    __syncthreads();
#pragma unroll
    for (int kk = 0; kk < 64; kk += 32) {
      bf16x8 af[4], bfr[JN];
#pragma unroll
      for (int i = 0; i < 4; ++i)
        af[i] = *(const bf16x8*)&As[wm + i * 16 + lane16][kk + quad * 8];
#pragma unroll
      for (int j = 0; j < JN; ++j)
        bfr[j] = *(const bf16x8*)&Bs[wn + j * 16 + lane16][kk + quad * 8];
#pragma unroll
      for (int i = 0; i < 4; ++i)
#pragma unroll
        for (int j = 0; j < JN; ++j)
          acc[i][j] = __builtin_amdgcn_mfma_f32_16x16x32_bf16(af[i], bfr[j], acc[i][j], 0, 0, 0);
    }
    __syncthreads();
  }

#pragma unroll
  for (int j = 0; j < JN; ++j) {
    int col = n0 + wn + j * 16 + lane16;
    float bv = bias ? bias[col] : 0.f;
#pragma unroll
    for (int i = 0; i < 4; ++i) {
#pragma unroll
      for (int r = 0; r < 4; ++r) {
        int row = m0 + wm + i * 16 + quad * 4 + r;
        float v = acc[i][j][r] + bv;
        if (RELU) v = fmaxf(v, 0.f);
        if (OUT_BF16)
          ((__bf16*)outp)[(size_t)row * N + col] = (__bf16)v;
        else
          ((float*)outp)[(size_t)row * N + col] = v;
      }
    }
  }
}

// ---- fused attention: gather kh|vh, inline qpk reduce, scores, softmax,
//      PV + folded Pv/pgx. one block per query token.
__global__ __launch_bounds__(256) void k_attnf(
    const __bf16* __restrict__ khv,       // (B*NK, 512): [kh|vh] per key
    const float* __restrict__ key_pos,    // (B, NK, 3)
    const float* __restrict__ query_pos,  // (BQ, 6)
    const int* __restrict__ idx,          // (BQ, S)
    const int* __restrict__ maskb,        // (BQ, S)
    const __bf16* __restrict__ qhb,       // (BQ, C)
    const float4* __restrict__ Pk,        // (C)
    const float4* __restrict__ Pv,        // (C)
    __bf16* __restrict__ aob) {           // (BQ, C)
  __shared__ __bf16 kvs[S_][520];
  __shared__ float qrow[C_];
  __shared__ float sc[H_][S_];
  __shared__ float pw[H_][S_];
  __shared__ float4 gx4[S_];
  __shared__ float4 pgxs[H_];
  __shared__ float4 qpks[H_];
  __shared__ int srow[S_], smask[S_];
  int bq = blockIdx.x, b = bq >> 10, t = threadIdx.x;

  if (t < S_) {
    int k = idx[(size_t)bq * S_ + t];
    srow[t] = b * NK_ + k;
    smask[t] = maskb[(size_t)bq * S_ + t];
    const float* kpp = key_pos + ((size_t)b * NK_ + k) * 3;
    const float* qp  = query_pos + (size_t)bq * 6;
    gx4[t] = make_float4(kpp[0] - qp[0], kpp[1] - qp[1], kpp[2] - qp[2], 1.f);
  }
  float qv_t = (float)qhb[(size_t)bq * C_ + t];
  qrow[t] = qv_t;
  {  // inline qpk: per-head reduce of qrow[t]*Pk[t] over 32 lanes
    float4 p = Pk[t];
    p.x *= qv_t; p.y *= qv_t; p.z *= qv_t; p.w *= qv_t;
#pragma unroll
    for (int off = 16; off >= 1; off >>= 1) {
      p.x += __shfl_xor(p.x, off);
      p.y += __shfl_xor(p.y, off);
      p.z += __shfl_xor(p.z, off);
      p.w += __shfl_xor(p.w, off);
    }
    if ((t & 31) == 0) {
      const float s = 0.17677669529663687f;
      qpks[t >> 5] = make_float4(p.x * s, p.y * s, p.z * s, p.w * s);
    }
  }
  __syncthreads();
  {  // gather khv rows: 16 rows x 1KB contiguous
    int s = t >> 4, c0 = (t & 15) * 32;
    const __bf16* src = khv + (size_t)srow[s] * 512 + c0;
    *(bf16x8*)&kvs[s][c0]      = *(const bf16x8*)&src[0];
    *(bf16x8*)&kvs[s][c0 + 8]  = *(const bf16x8*)&src[8];
    *(bf16x8*)&kvs[s][c0 + 16] = *(const bf16x8*)&src[16];
    *(bf16x8*)&kvs[s][c0 + 24] = *(const bf16x8*)&src[24];
  }
  __syncthreads();
  if (t < H_ * S_) {  // scores: 32-MAC per-head dot
    int h = t >> 4, s = t & (S_ - 1);
    float d = 0.f;
#pragma unroll
    for (int c0 = 0; c0 < 32; c0 += 8) {
      bf16x8 xv = *(const bf16x8*)&kvs[s][h * 32 + c0];
#pragma unroll
      for (int j = 0; j < 8; ++j) d += qrow[h * 32 + c0 + j] * (float)xv[j];
    }
    d *= 0.17677669529663687f;
    float4 g = gx4[s];
    float4 pk = qpks[h];
    d += g.x * pk.x + g.y * pk.y + g.z * pk.z + pk.w;
    if (smask[s]) d = -1e30f;
    sc[h][s] = d;
  }
  __syncthreads();
  if (t < H_) {  // softmax + pgx
    float mx = -3.4e38f;
#pragma unroll
    for (int s = 0; s < S_; ++s) mx = fmaxf(mx, sc[t][s]);
    float e[S_], sum = 0.f;
#pragma unroll
    for (int s = 0; s < S_; ++s) { e[s] = expf(sc[t][s] - mx); sum += e[s]; }
    float inv = 1.f / sum;
    float gxx = 0.f, gyy = 0.f, gzz = 0.f;
#pragma unroll
    for (int s = 0; s < S_; ++s) {
      float p = e[s] * inv;
      pw[t][s] = p;
      float4 g = gx4[s];
      gxx += p * g.x; gyy += p * g.y; gzz += p * g.z;
    }
    pgxs[t] = make_float4(gxx, gyy, gzz, 1.f);
  }
  __syncthreads();
  {  // PV
    int h = t >> 5;
    float a = 0.f;
#pragma unroll
    for (int s = 0; s < S_; ++s) a += pw[h][s] * (float)kvs[s][256 + t];
    float4 pv = Pv[t];
    float4 g = pgxs[h];
    a += g.x * pv.x + g.y * pv.y + g.z * pv.z + pv.w;
    aob[(size_t)bq * C_ + t] = (__bf16)a;
  }
}

// ---------------- LN1: out = LN(xa + xb)*g + b, fp32 + bf16 copies ----------
__global__ __launch_bounds__(256) void k_ln1(const float* __restrict__ xa,
                                             const float* __restrict__ xb,
                                             const float* __restrict__ g,
                                             const float* __restrict__ bb,
                                             float* __restrict__ outf,
                                             __bf16* __restrict__ outb) {
  int wid = (blockIdx.x * 256 + threadIdx.x) >> 6;
  int lane = threadIdx.x & 63;
  float4 va = *(const float4*)(xa + (size_t)wid * C_ + lane * 4);
  float4 vb = *(const float4*)(xb + (size_t)wid * C_ + lane * 4);
  float x0 = va.x + vb.x, x1 = va.y + vb.y, x2 = va.z + vb.z, x3 = va.w + vb.w;
  float s = x0 + x1 + x2 + x3;
#pragma unroll
  for (int off = 32; off >= 1; off >>= 1) s += __shfl_xor(s, off);
  float mean = s * (1.f / C_);
  float d0 = x0 - mean, d1 = x1 - mean, d2 = x2 - mean, d3 = x3 - mean;
  float v = d0 * d0 + d1 * d1 + d2 * d2 + d3 * d3;
#pragma unroll
  for (int off = 32; off >= 1; off >>= 1) v += __shfl_xor(v, off);
  float inv = 1.f / sqrtf(v * (1.f / C_) + EPS_);
  float4 g4 = *(const float4*)(g + lane * 4);
  float4 b4 = *(const float4*)(bb + lane * 4);
  float4 o;
  o.x = d0 * inv * g4.x + b4.x;
  o.y = d1 * inv * g4.y + b4.y;
  o.z = d2 * inv * g4.z + b4.z;
  o.w = d3 * inv * g4.w + b4.w;
  *(float4*)(outf + (size_t)wid * C_ + lane * 4) = o;
  __bf16* ob = outb + (size_t)wid * C_ + lane * 4;
  ob[0] = (__bf16)o.x; ob[1] = (__bf16)o.y; ob[2] = (__bf16)o.z; ob[3] = (__bf16)o.w;
}

// ---- fused LN2 + output transpose: out(B,C,NQ) = LN(x1+ff2)^T ------------
// grid (NQ/32, B), 256 threads; waves do LN on 8 rows each, then tiled write
__global__ __launch_bounds__(256) void k_lnt(const float* __restrict__ xa,
                                             const float* __restrict__ xb,
                                             const float* __restrict__ g,
                                             const float* __restrict__ bb,
                                             float* __restrict__ out) {
  __shared__ float buf[32][257];
  int z = blockIdx.y, nq0 = blockIdx.x * 32;
  int t = threadIdx.x;
  int w = t >> 6, lane = t & 63;
  float4 g4 = *(const float4*)(g + lane * 4);
  float4 b4 = *(const float4*)(bb + lane * 4);
#pragma unroll
  for (int rr = 0; rr < 8; ++rr) {
    int row = w * 8 + rr;
    size_t base = ((size_t)z * NQ_ + nq0 + row) * C_ + lane * 4;
    float4 va = *(const float4*)(xa + base);
    float4 vb = *(const float4*)(xb + base);
    float x0 = va.x + vb.x, x1 = va.y + vb.y, x2 = va.z + vb.z, x3 = va.w + vb.w;
    float s = x0 + x1 + x2 + x3;
#pragma unroll
    for (int off = 32; off >= 1; off >>= 1) s += __shfl_xor(s, off);
    float mean = s * (1.f / C_);
    float d0 = x0 - mean, d1 = x1 - mean, d2 = x2 - mean, d3 = x3 - mean;
    float v = d0 * d0 + d1 * d1 + d2 * d2 + d3 * d3;
#pragma unroll
    for (int off = 32; off >= 1; off >>= 1) v += __shfl_xor(v, off);
    float inv = 1.f / sqrtf(v * (1.f / C_) + EPS_);
    buf[row][lane * 4 + 0] = d0 * inv * g4.x + b4.x;
    buf[row][lane * 4 + 1] = d1 * inv * g4.y + b4.y;
    buf[row][lane * 4 + 2] = d2 * inv * g4.z + b4.z;
    buf[row][lane * 4 + 3] = d3 * inv * g4.w + b4.w;
  }
  __syncthreads();
  int tx = t & 31, ty = t >> 5;  // tx = nq_local, ty = c_group
#pragma unroll
  for (int ci = 0; ci < 32; ++ci) {
    int c = ci * 8 + ty;
    out[((size_t)z * C_ + c) * NQ_ + nq0 + tx] = buf[tx][c];
  }
}

extern "C" void kernel_launch(void* const* d_in, const int* in_sizes, int n_in,
                              void* d_out, int out_size, void* d_ws, size_t ws_size,
                              hipStream_t stream) {
  const float* query     = (const float*)d_in[0];
  const float* key       = (const float*)d_in[1];
  const float* query_pos = (const float*)d_in[2];
  const float* key_pos   = (const float*)d_in[3];
  const float* q_w = (const float*)d_in[4];  const float* q_b = (const float*)d_in[5];
  const float* k_w = (const float*)d_in[6];  const float* k_b = (const float*)d_in[7];
  const float* v_w = (const float*)d_in[8];  const float* v_b = (const float*)d_in[9];
  const float* o_w = (const float*)d_in[10]; const float* o_b = (const float*)d_in[11];
  const float* lin1_w = (const float*)d_in[12]; const float* lin1_b = (const float*)d_in[13];
  const float* lin2_w = (const float*)d_in[14]; const float* lin2_b = (const float*)d_in[15];
  const float* n1_g = (const float*)d_in[16]; const float* n1_b = (const float*)d_in[17];
  const float* n2_g = (const float*)d_in[18]; const float* n2_b = (const float*)d_in[19];
  const float* qpe_w = (const float*)d_in[20]; const float* qpe_b = (const float*)d_in[21];
  const float* kpe_w = (const float*)d_in[22]; const float* kpe_b = (const float*)d_in[23];
  float* out = (float*)d_out;

  const size_t BQc = (size_t)BQ_ * C_;
  float* w = (float*)d_ws;
  size_t o = 0;
  // ---- workspace carve (~100 MB) ----
  __bf16* keyTb = (__bf16*)(w + o); o += (size_t)B_ * NK_ * C_ / 2;   // 16.8 MB
  float* qtok  = w + o; o += BQc;
  float* x1    = w + o; o += BQc;
  float* attno = w + o; o += BQc;                                     // ff2o overlay
  __bf16* khvbuf = (__bf16*)(w + o); o += (size_t)B_ * NK_ * 512 / 2; // 33.5 MB; ff1b overlay
  __bf16* qinb = (__bf16*)(w + o); o += BQc / 2;
  __bf16* qhb  = (__bf16*)(w + o); o += BQc / 2;
  __bf16* aob  = (__bf16*)(w + o); o += BQc / 2;
  __bf16* x1b  = (__bf16*)(w + o); o += BQc / 2;
  __bf16* qwb  = (__bf16*)(w + o); o += (size_t)C_ * C_ / 2;
  __bf16* kvwb = (__bf16*)(w + o); o += (size_t)C_ * C_;              // (512,256) = k_w ++ v_w
  __bf16* owb  = (__bf16*)(w + o); o += (size_t)C_ * C_ / 2;
  __bf16* l1b  = (__bf16*)(w + o); o += (size_t)C_ * FF_ / 2;
  __bf16* l2b  = (__bf16*)(w + o); o += (size_t)C_ * FF_ / 2;
  float4* Pk   = (float4*)(w + o); o += C_ * 4;
  float4* Pv   = (float4*)(w + o); o += C_ * 4;
  int* idxb  = (int*)(w + o); o += (size_t)BQ_ * S_;
  int* maskb = (int*)(w + o); o += (size_t)BQ_ * S_;
  __bf16* ff1b = khvbuf;    // khv dead after attnf
  float* ff2o  = attno;     // attno dead after LN1

  dim3 tb(32, 8);
  // 1. key transpose -> bf16 (B, NK, C)
  k_transb<<<dim3(NK_ / 32, C_ / 32, B_), tb, 0, stream>>>(key, keyTb, C_, NK_);
  // 2. fused query transpose + qpe (qtok fp32, qinb bf16)
  k_transq<<<dim3(NQ_ / 32, C_ / 32, B_), tb, 0, stream>>>(query, query_pos,
                                                           qpe_w, qpe_b, qtok, qinb);
  // 3. all weight casts
  CvtArgs ca;
  ca.src[0] = q_w; ca.dst[0] = qwb;
  ca.src[1] = k_w; ca.dst[1] = kvwb;
  ca.src[2] = v_w; ca.dst[2] = kvwb + (size_t)C_ * C_;
  ca.src[3] = o_w; ca.dst[3] = owb;
  ca.src[4] = lin1_w; ca.dst[4] = l1b;
  ca.src[5] = lin2_w; ca.dst[5] = l2b;
  k_cvt_all<<<1280, 256, 0, stream>>>(ca);
  // 4. folded kpe projections (Pk, Pv in one launch)
  k_pproj2<<<dim3(8, 2), 256, 0, stream>>>(k_w, k_b, v_w, v_b, kpe_w, kpe_b, Pk, Pv);
  // 5. box query
  k_boxq<<<BQ_ / 4, 256, 0, stream>>>(key_pos, query_pos, idxb, maskb);
  // 6. khv = key_feat @ [k_w|v_w]^T per unique key
  k_gemm_bf16<128, 0, 1><<<dim3(512 / 128, B_ * NK_ / 128), 256, 0, stream>>>(
      keyTb, kvwb, nullptr, khvbuf, B_ * NK_, 512, C_);
  // 7. qh = qin @ q_w.T + q_b
  k_gemm_bf16<64, 0, 1><<<dim3(C_ / 64, BQ_ / 128), 256, 0, stream>>>(qinb, qwb, q_b, qhb, BQ_, C_, C_);
  // 8. fused attention (qpk inline)
  k_attnf<<<BQ_, 256, 0, stream>>>(khvbuf, key_pos, query_pos, idxb, maskb,
                                   qhb, Pk, Pv, aob);
  // 9. o projection (fp32 out)
  k_gemm_bf16<64, 0, 0><<<dim3(C_ / 64, BQ_ / 128), 256, 0, stream>>>(aob, owb, o_b, attno, BQ_, C_, C_);
  // 10. x1 = LN(qtok + attno), fp32 + bf16
  k_ln1<<<BQ_ / 4, 256, 0, stream>>>(qtok, attno, n1_g, n1_b, x1, x1b);
  // 11. ff1(bf16) = relu(x1 @ lin1.T + b)   [overlays khvbuf]
  k_gemm_bf16<128, 1, 1><<<dim3(FF_ / 128, BQ_ / 128), 256, 0, stream>>>(x1b, l1b, lin1_b, ff1b, BQ_, FF_, C_);
  // 12. ff2(fp32) = ff1 @ lin2.T + b        [overlays attno]
  k_gemm_bf16<64, 0, 0><<<dim3(C_ / 64, BQ_ / 128), 256, 0, stream>>>(ff1b, l2b, lin2_b, ff2o, BQ_, C_, FF_);
  // 13. out = transpose(LN(x1 + ff2))
  k_lnt<<<dim3(NQ_ / 32, B_), 256, 0, stream>>>(x1, ff2o, n2_g, n2_b, out);
}